// Round 13
// baseline (312.443 us; speedup 1.0000x reference)
//
#include <hip/hip_runtime.h>
#include <hip/hip_bf16.h>
#include <stdint.h>

#define SEQ 4096
#define DM 2048
#define NH 16
#define HD 128

typedef __attribute__((ext_vector_type(4)))  float f32x4;
typedef __attribute__((ext_vector_type(16))) float f32x16;
typedef __attribute__((ext_vector_type(8)))  short bf16x8;
typedef __attribute__((ext_vector_type(4)))  float float4_t;
typedef __attribute__((ext_vector_type(4)))  short s16x4;
typedef __attribute__((ext_vector_type(2)))  int   i32x2;
typedef __attribute__((ext_vector_type(2)))  unsigned u32x2;

__device__ __forceinline__ short f2bf(float f) {
  union { float f; unsigned u; } c; c.f = f;
  unsigned u = c.u;
  u += 0x7FFFu + ((u >> 16) & 1u);   // RNE
  return (short)(u >> 16);
}

__device__ __forceinline__ int cvtpk(float lo, float hi) {
  int r;
  asm("v_cvt_pk_bf16_f32 %0, %1, %2" : "=v"(r) : "v"(lo), "v"(hi));
  return r;
}

__device__ __forceinline__ float exp2r(float x) {   // raw v_exp_f32
  return __builtin_amdgcn_exp2f(x);
}

__device__ __forceinline__ void async16(const void* g, void* l) {
  __builtin_amdgcn_global_load_lds((const __attribute__((address_space(1))) void*)g,
                                   (__attribute__((address_space(3))) void*)l, 16, 0, 0);
}

__global__ __launch_bounds__(256) void rope_tables_kernel(float2* __restrict__ tab) {
  int idx = blockIdx.x * 256 + threadIdx.x;  // SEQ*64
  int s = idx >> 6, j = idx & 63;
  float invf = expf(-(float)j * (9.210340371976184f / 64.0f)); // 10000^(-j/64)
  float ang = (float)s * invf;
  tab[idx] = make_float2(cosf(ang), sinf(ang));
}

__global__ __launch_bounds__(256) void f32_to_bf16_kernel(const float* __restrict__ in,
                                                          short* __restrict__ out, int n4) {
  int stride = gridDim.x * 256;
  for (int i = blockIdx.x * 256 + threadIdx.x; i < n4; i += stride) {
    float4_t v = ((const float4_t*)in)[i];
    s16x4 r;
    #pragma unroll
    for (int u = 0; u < 4; u++) r[u] = f2bf(v[u]);
    ((s16x4*)out)[i] = r;
  }
}

// ---------------- GEMM: bf16 in, global_load_lds staging, BK=64 ------------
// C[M][N] = A[M][K] * B[N][K]^T. OUT_MODE: 0 f32, 2 bf16 transposed.
template<int OUT_MODE>
__global__ __launch_bounds__(256) void gemm_async_kernel(
    const short* __restrict__ A, const short* __restrict__ B,
    void* __restrict__ Cp, int M, int N, int K) {
  __shared__ short As[128 * 64];
  __shared__ short Bs[128 * 64];
  const int t = threadIdx.x, lane = t & 63, w = t >> 6;
  const int wr = w >> 1, wc = w & 1;
  const size_t Mbase = (size_t)blockIdx.x * 128;
  const size_t Nbase = (size_t)blockIdx.y * 128;
  f32x4 acc[4][4] = {};

  for (int k0 = 0; k0 < K; k0 += 64) {
    __syncthreads();
    #pragma unroll
    for (int c = 0; c < 4; c++) {
      int ob = w * 4096 + c * 1024;           // uniform per wave
      int o = ob + lane * 16;
      int row = o >> 7;
      int cb = (o & 127) ^ ((row & 7) << 4);
      async16((const char*)A + ((Mbase + row) * (size_t)K + k0) * 2 + cb, (char*)As + ob);
      async16((const char*)B + ((Nbase + row) * (size_t)K + k0) * 2 + cb, (char*)Bs + ob);
    }
    __syncthreads();

    bf16x8 a[2][4], b[2][4];
    #pragma unroll
    for (int ks = 0; ks < 2; ks++) {
      #pragma unroll
      for (int m = 0; m < 4; m++) {
        int row = wr * 64 + m * 16 + (lane & 15);
        int chunk = ks * 64 + (lane >> 4) * 16;
        a[ks][m] = *(const bf16x8*)((const char*)As + row * 128 + (chunk ^ ((row & 7) << 4)));
      }
      #pragma unroll
      for (int n = 0; n < 4; n++) {
        int row = wc * 64 + n * 16 + (lane & 15);
        int chunk = ks * 64 + (lane >> 4) * 16;
        b[ks][n] = *(const bf16x8*)((const char*)Bs + row * 128 + (chunk ^ ((row & 7) << 4)));
      }
    }
    #pragma unroll
    for (int ks = 0; ks < 2; ks++)
      #pragma unroll
      for (int m = 0; m < 4; m++)
        #pragma unroll
        for (int n = 0; n < 4; n++)
          acc[m][n] = __builtin_amdgcn_mfma_f32_16x16x32_bf16(a[ks][m], b[ks][n], acc[m][n], 0, 0, 0);
  }

  #pragma unroll
  for (int m = 0; m < 4; m++)
    #pragma unroll
    for (int n = 0; n < 4; n++)
      #pragma unroll
      for (int j = 0; j < 4; j++) {
        size_t row = Mbase + wr * 64 + m * 16 + (lane >> 4) * 4 + j;
        size_t col = Nbase + wc * 64 + n * 16 + (lane & 15);
        float v = acc[m][n][j];
        if (OUT_MODE == 0) ((float*)Cp)[row * N + col] = v;
        else               ((short*)Cp)[col * (size_t)M + row] = f2bf(v);
      }
}

// ---------------- GEMM + fused RoPE epilogue (Q/K projections) -------------
// Wave tiling 4x1: wave w owns rows w*32..w*32+31, all 128 cols (one head).
// IS_Q folds log2e/sqrt(HD) into Q so attention works in exp2 domain.
template<int IS_Q>
__global__ __launch_bounds__(256) void gemm_rope_kernel(
    const short* __restrict__ A, const short* __restrict__ B,
    short* __restrict__ C, const float2* __restrict__ tab) {
  __shared__ short As[128 * 64];
  __shared__ short Bs[128 * 64];
  const int t = threadIdx.x, lane = t & 63, w = t >> 6;
  const size_t Mbase = (size_t)blockIdx.x * 128;
  const size_t Nbase = (size_t)blockIdx.y * 128;
  const int K = DM;
  f32x4 acc[2][8] = {};

  for (int k0 = 0; k0 < K; k0 += 64) {
    __syncthreads();
    #pragma unroll
    for (int c = 0; c < 4; c++) {
      int ob = w * 4096 + c * 1024;
      int o = ob + lane * 16;
      int row = o >> 7;
      int cb = (o & 127) ^ ((row & 7) << 4);
      async16((const char*)A + ((Mbase + row) * (size_t)K + k0) * 2 + cb, (char*)As + ob);
      async16((const char*)B + ((Nbase + row) * (size_t)K + k0) * 2 + cb, (char*)Bs + ob);
    }
    __syncthreads();

    bf16x8 a[2][2], b[2][8];
    #pragma unroll
    for (int ks = 0; ks < 2; ks++) {
      #pragma unroll
      for (int m = 0; m < 2; m++) {
        int row = w * 32 + m * 16 + (lane & 15);
        int chunk = ks * 64 + (lane >> 4) * 16;
        a[ks][m] = *(const bf16x8*)((const char*)As + row * 128 + (chunk ^ ((row & 7) << 4)));
      }
      #pragma unroll
      for (int n = 0; n < 8; n++) {
        int row = n * 16 + (lane & 15);
        int chunk = ks * 64 + (lane >> 4) * 16;
        b[ks][n] = *(const bf16x8*)((const char*)Bs + row * 128 + (chunk ^ ((row & 7) << 4)));
      }
    }
    #pragma unroll
    for (int ks = 0; ks < 2; ks++)
      #pragma unroll
      for (int m = 0; m < 2; m++)
        #pragma unroll
        for (int n = 0; n < 8; n++)
          acc[m][n] = __builtin_amdgcn_mfma_f32_16x16x32_bf16(a[ks][m], b[ks][n], acc[m][n], 0, 0, 0);
  }

  // Q: scale = log2(e)/sqrt(128) so attention uses exp2 directly.
  const float SC = IS_Q ? 0.12751746f : 1.0f;
  #pragma unroll
  for (int m = 0; m < 2; m++)
    #pragma unroll
    for (int n = 0; n < 4; n++)
      #pragma unroll
      for (int j = 0; j < 4; j++) {
        int row = (int)Mbase + w * 32 + m * 16 + (lane >> 4) * 4 + j;   // seq pos
        int dj = n * 16 + (lane & 15);                                  // 0..63
        float2 cs = tab[row * 64 + dj];
        float cc = cs.x * SC, ss = cs.y * SC;
        float r1 = acc[m][n][j], r2 = acc[m][n + 4][j];
        C[(size_t)row * DM + Nbase + dj]      = f2bf(r1 * cc - r2 * ss);
        C[(size_t)row * DM + Nbase + dj + 64] = f2bf(r2 * cc + r1 * ss);
      }
}

// ---------------- flash attention v12: 4-wave blocks, 4 blocks/CU ----------
// Diagnosis r9-r12: 8-wave blocks = 2 waves/SIMD, phase-locked by one barrier
// -> MFMA/VALU/LDS pipes serialize (step = ~sum, 3900cy). Fix via block-level
// parallelism: 256-thr blocks (2 q-strips x 2 kv-halves), QBLK=64, single-
// buffered 32.5KB LDS -> 4 independent blocks/CU; their barrier domains
// de-phase naturally and staging stalls hide under other blocks' compute.
// Grid 1024 = 16 heads x 64 q-tiles, longest-tile-FIRST (LPT backfill).
// Inner math verbatim from validated r9/r10: S^T=mfma(K,Q), exp2 domain,
// T12 cvt_pk+permlane, defer-max, packed-V^T swizzle, LDS merge.
__global__ __launch_bounds__(256) void flash_attn12_kernel(
    const short* __restrict__ Q, const short* __restrict__ K,
    const short* __restrict__ VT, short* __restrict__ O) {
  // LDS: Ks [0,16K): 64 key-rows x 256B, XOR (row&15)<<4.
  //      Vs [16K,32K): 64 rows x 256B, 2 d-rows packed per row.
  //      ml [32768,33280): strip s at +s*256.
  // Merge overlay (after kv loop, Ks/Vs dead): strip s Opart = [s*16K,+16K)
  // fp32 [128 d][32 q].
  __shared__ __align__(16) char LB[33280];
  const int t = threadIdx.x, lane = t & 63, w = t >> 6;   // w: 0..3
  const int hi = lane >> 5, c31 = lane & 31;
  const int s = w & 1, v = w >> 1;                // q-strip, kv-half
  const int id = blockIdx.x;                      // 0..1023
  const int h  = (id & 7) * 2 + ((id >> 3) & 1);  // 2 heads per XCD
  const int qt = 63 - (id >> 4);                  // 64-row q-tile, longest first
  const int q0 = qt * 64;
  const int nt = qt + 1;                          // 64-key steps
  const int qrow = q0 + s * 32 + c31;             // this lane's q-row

  auto stage = [&](int kt) {
    #pragma unroll
    for (int it = 0; it < 4; it++) {
      const int ob = w * 4096 + it * 1024;        // wave-uniform LDS byte base
      const int o  = ob + lane * 16;
      const int row = o >> 8;                     // 0..63
      const int xs = (o & 255) ^ ((row & 15) << 4);
      { // K: LDS[row*256+x] = K[kt*64+row][xs]
        const size_t src = ((size_t)(kt * 64 + row) * DM + h * HD) * 2 + xs;
        async16((const char*)K + src, LB + ob); }
      { // V^T packed: d = 2*row + (xs>>7), key byte = xs&127
        const int d = 2 * row + (xs >> 7);
        const size_t src = ((size_t)(h * HD + d) * SEQ + (size_t)kt * 64) * 2
                         + (size_t)(xs & 127);
        async16((const char*)VT + src, LB + 16384 + ob); }
    }
  };

  // Q fragments (B-operand): lane holds Q[qrow][16ss+8hi .. +7]
  bf16x8 qf[8];
  #pragma unroll
  for (int ss = 0; ss < 8; ss++)
    qf[ss] = *(const bf16x8*)(Q + (size_t)qrow * DM + h * HD + ss * 16 + hi * 8);

  f32x16 oacc[4] = {};
  float m = -3.0e38f, l = 0.f;

  for (int kt = 0; kt < nt; kt++) {
    __syncthreads();              // prior step's Ks/Vs reads done
    stage(kt);
    __syncthreads();              // staged loads landed (sync drains vmcnt)

    if (kt * 64 + v * 32 <= q0 + s * 32 + 31) {   // wave has unmasked work
      const char* KsB = LB;
      const char* VsB = LB + 16384;

      // ---- S^T = K Q^T : keys [32v,32v+32), q-col = c31 ----
      f32x16 sacc = {};
      __builtin_amdgcn_s_setprio(1);
      #pragma unroll
      for (int ss = 0; ss < 8; ss++) {
        int row = v * 32 + c31;
        bf16x8 kf = *(const bf16x8*)(KsB + row * 256
                                     + ((ss * 32 + hi * 16) ^ ((row & 15) << 4)));
        sacc = __builtin_amdgcn_mfma_f32_32x32x16_bf16(kf, qf[ss], sacc, 0, 0, 0);
      }
      __builtin_amdgcn_s_setprio(0);

      // ---- per-q max over the wave's 32 keys (log2 domain) ----
      float t0[8];
      #pragma unroll
      for (int r = 0; r < 8; r++) t0[r] = fmaxf(sacc[r], sacc[r + 8]);
      #pragma unroll
      for (int d = 4; d > 0; d >>= 1)
        #pragma unroll
        for (int r = 0; r < 4; r++) if (r < d) t0[r] = fmaxf(t0[r], t0[r + d]);
      float mx = t0[0];
      i32x2 mm = __builtin_amdgcn_permlane32_swap(__float_as_int(mx), __float_as_int(mx),
                                                  false, false);
      mx = fmaxf(__int_as_float(mm.x), __int_as_float(mm.y));

      // ---- defer-max rescale (THR = 8/ln2 in log2 domain) ----
      if (__any(mx > m + 11.5416f)) {
        float mn = fmaxf(m, mx);
        float al = exp2r(m - mn);
        m = mn; l *= al;
        #pragma unroll
        for (int g = 0; g < 4; g++)
          #pragma unroll
          for (int r = 0; r < 16; r++) oacc[g][r] *= al;
      }

      // ---- exp2 + causal mask ----
      const int rel = qrow - kt * 64 - v * 32;     // keep key_local <= rel
      const bool maskT = (kt * 64 + v * 32 + 31) > (q0 + s * 32);
      #pragma unroll
      for (int r = 0; r < 16; r++) {
        float e = exp2r(sacc[r] - m);
        if (maskT) {
          int kl = (r & 3) + 8 * (r >> 2) + 4 * hi;
          e = (kl > rel) ? 0.f : e;
        }
        sacc[r] = e;
      }

      // ---- per-(hi,q) sum -> l ----
      float s0[8];
      #pragma unroll
      for (int r = 0; r < 8; r++) s0[r] = sacc[r] + sacc[r + 8];
      #pragma unroll
      for (int d = 4; d > 0; d >>= 1)
        #pragma unroll
        for (int r = 0; r < 4; r++) if (r < d) s0[r] = s0[r] + s0[r + d];
      l += s0[0];

      // ---- P^T B-fragments via cvt_pk + permlane32_swap (T12) ----
      bf16x8 pa[2];
      #pragma unroll
      for (int sg = 0; sg < 2; sg++) {
        int q0a = cvtpk(sacc[8 * sg + 0], sacc[8 * sg + 1]);
        int q1a = cvtpk(sacc[8 * sg + 2], sacc[8 * sg + 3]);
        int q0b = cvtpk(sacc[8 * sg + 4], sacc[8 * sg + 5]);
        int q1b = cvtpk(sacc[8 * sg + 6], sacc[8 * sg + 7]);
        i32x2 r0 = __builtin_amdgcn_permlane32_swap(q0a, q0b, false, false);
        i32x2 r1 = __builtin_amdgcn_permlane32_swap(q1a, q1b, false, false);
        union { int d[4]; bf16x8 vv; } u;
        u.d[0] = r0.x; u.d[1] = r1.x; u.d[2] = r0.y; u.d[3] = r1.y;
        pa[sg] = u.vv;
      }

      // ---- partial O^T += V^T P^T over keys [32v, 32v+32) ----
      // V^T packed layout: d at LDS row d>>1, x = (d&1)*128 + key byte.
      __builtin_amdgcn_s_setprio(1);
      #pragma unroll
      for (int ks = 0; ks < 2; ks++)
        #pragma unroll
        for (int g = 0; g < 4; g++) {
          int d = g * 32 + c31;
          int row = d >> 1;
          int x = (d & 1) * 128 + v * 64 + ks * 32 + hi * 16;
          bf16x8 vf = *(const bf16x8*)(VsB + row * 256 + (x ^ ((row & 15) << 4)));
          oacc[g] = __builtin_amdgcn_mfma_f32_32x32x16_bf16(vf, pa[ks], oacc[g], 0, 0, 0);
        }
      __builtin_amdgcn_s_setprio(0);
    }
  }
  __syncthreads();   // last step's Ks/Vs reads done before overlay reuse

  // ---- combine l across the hi pair (m already shared) ----
  i32x2 lr = __builtin_amdgcn_permlane32_swap(__float_as_int(l), __float_as_int(l),
                                              false, false);
  l = __int_as_float(lr.x) + __int_as_float(lr.y);

  // ---- merge the 2 kv-half partials: v==1 publishes, v==0 folds+writes ----
  if (v == 1) {
    float* Op = (float*)(LB + s * 16384);          // [128 d][32 q]
    #pragma unroll
    for (int g = 0; g < 4; g++)
      #pragma unroll
      for (int rr = 0; rr < 16; rr++) {
        int d = g * 32 + (rr & 3) + 8 * (rr >> 2) + 4 * hi;
        Op[d * 32 + c31] = oacc[g][rr];
      }
    if (hi == 0) {
      float* mm2 = (float*)(LB + 32768 + s * 256) + c31 * 2;
      mm2[0] = m; mm2[1] = l;
    }
  }
  __syncthreads();
  if (v == 0) {
    const float* mm2 = (const float*)(LB + 32768 + s * 256) + c31 * 2;
    float lB = mm2[1];
    float mB = (lB > 0.f) ? mm2[0] : -3.0e38f;
    float ms = fmaxf(m, mB);
    float aA = exp2r(m - ms), aB = exp2r(mB - ms);
    float linv = 1.0f / (l * aA + lB * aB);
    float sA = aA * linv, sB = aB * linv;
    const float* Op = (const float*)(LB + s * 16384);
    #pragma unroll
    for (int g = 0; g < 4; g++)
      #pragma unroll
      for (int tt = 0; tt < 4; tt++) {
        float o[4];
        #pragma unroll
        for (int e = 0; e < 4; e++) {
          int d = g * 32 + e + 8 * tt + 4 * hi;
          o[e] = oacc[g][4 * tt + e] * sA + Op[d * 32 + c31] * sB;
        }
        u32x2 pk;
        pk.x = (unsigned)cvtpk(o[0], o[1]);
        pk.y = (unsigned)cvtpk(o[2], o[3]);
        *(u32x2*)(O + (size_t)qrow * DM + h * HD + g * 32 + tt * 8 + hi * 4) = pk;
      }
  }
}

extern "C" void kernel_launch(void* const* d_in, const int* in_sizes, int n_in,
                              void* d_out, int out_size, void* d_ws, size_t ws_size,
                              hipStream_t stream) {
  const float* x  = (const float*)d_in[0];
  const float* wq = (const float*)d_in[1];
  const float* wk = (const float*)d_in[2];
  const float* wv = (const float*)d_in[3];
  const float* wo = (const float*)d_in[4];
  float* out = (float*)d_out;

  const size_t SQDMs = (size_t)SEQ * DM;   // 8M elements
  short* Qb   = (short*)d_ws;
  short* Kb   = Qb + SQDMs;
  short* VTb  = Kb + SQDMs;
  short* Cb   = VTb + SQDMs;
  short* xbf  = Cb + SQDMs;
  short* wbuf = xbf + SQDMs;
  float2* tab = (float2*)(wbuf + (size_t)DM * DM);

  rope_tables_kernel<<<SEQ * 64 / 256, 256, 0, stream>>>(tab);
  f32_to_bf16_kernel<<<2048, 256, 0, stream>>>(x, xbf, (int)(SQDMs / 4));

  dim3 g(SEQ / 128, DM / 128);
  f32_to_bf16_kernel<<<2048, 256, 0, stream>>>(wq, wbuf, DM * DM / 4);
  gemm_rope_kernel<1><<<g, 256, 0, stream>>>(xbf, wbuf, Qb, tab);
  f32_to_bf16_kernel<<<2048, 256, 0, stream>>>(wk, wbuf, DM * DM / 4);
  gemm_rope_kernel<0><<<g, 256, 0, stream>>>(xbf, wbuf, Kb, tab);
  f32_to_bf16_kernel<<<2048, 256, 0, stream>>>(wv, wbuf, DM * DM / 4);
  gemm_async_kernel<2><<<g, 256, 0, stream>>>(xbf, wbuf, VTb, SEQ, DM, DM);

  flash_attn12_kernel<<<1024, 256, 0, stream>>>(Qb, Kb, VTb, Cb);

  f32_to_bf16_kernel<<<2048, 256, 0, stream>>>(wo, wbuf, DM * DM / 4);
  gemm_async_kernel<0><<<g, 256, 0, stream>>>(Cb, wbuf, out, SEQ, DM, DM);
}

// Round 14
// 283.475 us; speedup vs baseline: 1.1022x; 1.1022x over previous
//
#include <hip/hip_runtime.h>
#include <hip/hip_bf16.h>
#include <stdint.h>

#define SEQ 4096
#define DM 2048
#define NH 16
#define HD 128

typedef __attribute__((ext_vector_type(4)))  float f32x4;
typedef __attribute__((ext_vector_type(16))) float f32x16;
typedef __attribute__((ext_vector_type(8)))  short bf16x8;
typedef __attribute__((ext_vector_type(4)))  float float4_t;
typedef __attribute__((ext_vector_type(4)))  short s16x4;
typedef __attribute__((ext_vector_type(2)))  int   i32x2;
typedef __attribute__((ext_vector_type(2)))  unsigned u32x2;

__device__ __forceinline__ short f2bf(float f) {
  union { float f; unsigned u; } c; c.f = f;
  unsigned u = c.u;
  u += 0x7FFFu + ((u >> 16) & 1u);   // RNE
  return (short)(u >> 16);
}

__device__ __forceinline__ int cvtpk(float lo, float hi) {
  int r;
  asm("v_cvt_pk_bf16_f32 %0, %1, %2" : "=v"(r) : "v"(lo), "v"(hi));
  return r;
}

__device__ __forceinline__ float exp2r(float x) {   // raw v_exp_f32
  return __builtin_amdgcn_exp2f(x);
}

__device__ __forceinline__ void async16(const void* g, void* l) {
  __builtin_amdgcn_global_load_lds((const __attribute__((address_space(1))) void*)g,
                                   (__attribute__((address_space(3))) void*)l, 16, 0, 0);
}

__global__ __launch_bounds__(256) void rope_tables_kernel(float2* __restrict__ tab) {
  int idx = blockIdx.x * 256 + threadIdx.x;  // SEQ*64
  int s = idx >> 6, j = idx & 63;
  float invf = expf(-(float)j * (9.210340371976184f / 64.0f)); // 10000^(-j/64)
  float ang = (float)s * invf;
  tab[idx] = make_float2(cosf(ang), sinf(ang));
}

__global__ __launch_bounds__(256) void f32_to_bf16_kernel(const float* __restrict__ in,
                                                          short* __restrict__ out, int n4) {
  int stride = gridDim.x * 256;
  for (int i = blockIdx.x * 256 + threadIdx.x; i < n4; i += stride) {
    float4_t v = ((const float4_t*)in)[i];
    s16x4 r;
    #pragma unroll
    for (int u = 0; u < 4; u++) r[u] = f2bf(v[u]);
    ((s16x4*)out)[i] = r;
  }
}

// ---------------- 8-phase GEMM: BM=256 BN=128 BK=64, 512 thr, 1 block/CU ---
// C[M][N] = A[M][K] * B[N][K]^T, M=SEQ N=DM K=DM. Wave w owns rows w*32..+31,
// all 128 cols. Per K-tile: 4 phases {ds_read subtile; stage 2 loads of tile
// kt+2; barrier; lgkmcnt(0); 8 MFMA; barrier}; vmcnt(6) once per tile
// (phase 3) -- staged loads stay in flight across barriers (T3+T4).
// 3-deep LDS buffers: stage target = tile kt-1's buffer, safe after the
// shared barrier. T2 swizzle: col ^= (row&7)<<4 on 128B rows.
// MODE: 0 = f32 C; 1 = bf16 + RoPE (Q scale log2e/sqrt(HD)); 2 = bf16 + RoPE
// (K, scale 1); 3 = bf16 transposed (V^T output [N][M]).
template<int MODE>
__global__ __launch_bounds__(512) void gemm8p_kernel(
    const short* __restrict__ A, const short* __restrict__ B,
    void* __restrict__ Cp, const float2* __restrict__ tab) {
  constexpr int MM = SEQ, NN = DM, K = DM;
  // As: 3 bufs x 32KB (256 rows x 128B) at 0; Bs: 3 x 16KB (128 x 128B) at 98304.
  __shared__ __align__(16) char LB[147456];
  const int t = threadIdx.x, lane = t & 63, w = t >> 6;   // w: 0..7
  const size_t Mbase = (size_t)blockIdx.x * 256;
  const size_t Nbase = (size_t)blockIdx.y * 128;
  const int nt = K / 64;

  auto stageA = [&](int kt, int half) {   // half: rows 0-127 / 128-255
    const int buf = kt % 3, k0 = kt * 64;
    #pragma unroll
    for (int it = 0; it < 2; it++) {
      const int ob = half * 16384 + it * 8192 + w * 1024;  // wave-uniform base
      const int o = ob + lane * 16;
      const int row = o >> 7;
      const int col = (o & 127) ^ ((row & 7) << 4);
      async16((const char*)A + ((Mbase + row) * (size_t)K + k0) * 2 + col,
              LB + buf * 32768 + ob);
    }
  };
  auto stageB = [&](int kt) {
    const int buf = kt % 3, k0 = kt * 64;
    #pragma unroll
    for (int it = 0; it < 2; it++) {
      const int ob = it * 8192 + w * 1024;
      const int o = ob + lane * 16;
      const int row = o >> 7;
      const int col = (o & 127) ^ ((row & 7) << 4);
      async16((const char*)B + ((Nbase + row) * (size_t)K + k0) * 2 + col,
              LB + 98304 + buf * 16384 + ob);
    }
  };

  f32x4 acc[2][8] = {};

  stageA(0, 0); stageA(0, 1); stageB(0);
  stageA(1, 0); stageA(1, 1); stageB(1);
  asm volatile("s_waitcnt vmcnt(6)" ::: "memory");   // tile 0 landed
  __builtin_amdgcn_s_barrier();

  for (int kt = 0; kt < nt; kt++) {
    const char* AsB = LB + (kt % 3) * 32768;
    const char* BsB = LB + 98304 + (kt % 3) * 16384;
    const bool pre = (kt + 2 < nt);
    bf16x8 a[2][2];
    #pragma unroll
    for (int p = 0; p < 4; p++) {
      bf16x8 bb[2][2];
      if (p == 0) {
        #pragma unroll
        for (int ks = 0; ks < 2; ks++)
          #pragma unroll
          for (int m = 0; m < 2; m++) {
            int row = w * 32 + m * 16 + (lane & 15);
            a[ks][m] = *(const bf16x8*)(AsB + row * 128
                        + ((ks * 64 + (lane >> 4) * 16) ^ ((row & 7) << 4)));
          }
      }
      #pragma unroll
      for (int ks = 0; ks < 2; ks++)
        #pragma unroll
        for (int j = 0; j < 2; j++) {
          int row = (2 * p + j) * 16 + (lane & 15);
          bb[ks][j] = *(const bf16x8*)(BsB + row * 128
                       + ((ks * 64 + (lane >> 4) * 16) ^ ((row & 7) << 4)));
        }
      if (p == 0 && pre) stageA(kt + 2, 0);
      if (p == 1 && pre) stageA(kt + 2, 1);
      if (p == 2 && pre) stageB(kt + 2);
      if (p == 3) asm volatile("s_waitcnt vmcnt(6)" ::: "memory");  // kt+1 landed
      __builtin_amdgcn_s_barrier();
      asm volatile("s_waitcnt lgkmcnt(0)" ::: "memory");
      __builtin_amdgcn_sched_barrier(0);
      __builtin_amdgcn_s_setprio(1);
      #pragma unroll
      for (int ks = 0; ks < 2; ks++)
        #pragma unroll
        for (int m = 0; m < 2; m++)
          #pragma unroll
          for (int j = 0; j < 2; j++)
            acc[m][2 * p + j] = __builtin_amdgcn_mfma_f32_16x16x32_bf16(
                a[ks][m], bb[ks][j], acc[m][2 * p + j], 0, 0, 0);
      __builtin_amdgcn_s_setprio(0);
      __builtin_amdgcn_s_barrier();
    }
  }

  if (MODE == 1 || MODE == 2) {
    const float SC = (MODE == 1) ? 0.12751746f : 1.0f;  // log2e/sqrt(128) | 1
    #pragma unroll
    for (int m = 0; m < 2; m++)
      #pragma unroll
      for (int n = 0; n < 4; n++)
        #pragma unroll
        for (int j = 0; j < 4; j++) {
          int row = (int)Mbase + w * 32 + m * 16 + (lane >> 4) * 4 + j;  // seq
          int dj = n * 16 + (lane & 15);                                 // 0..63
          float2 cs = tab[row * 64 + dj];
          float cc = cs.x * SC, ss = cs.y * SC;
          float r1 = acc[m][n][j], r2 = acc[m][n + 4][j];
          short* C = (short*)Cp;
          C[(size_t)row * NN + Nbase + dj]      = f2bf(r1 * cc - r2 * ss);
          C[(size_t)row * NN + Nbase + dj + 64] = f2bf(r2 * cc + r1 * ss);
        }
  } else {
    #pragma unroll
    for (int m = 0; m < 2; m++)
      #pragma unroll
      for (int n = 0; n < 8; n++)
        #pragma unroll
        for (int j = 0; j < 4; j++) {
          size_t row = Mbase + w * 32 + m * 16 + (lane >> 4) * 4 + j;
          size_t col = Nbase + n * 16 + (lane & 15);
          float v = acc[m][n][j];
          if (MODE == 0) ((float*)Cp)[row * NN + col] = v;
          else           ((short*)Cp)[col * (size_t)MM + row] = f2bf(v);
        }
  }
}

// ---------------- flash attention (r10 best: 107 us, conflict-free) --------
// 512 thr, 8 waves = 4 q-strips (32 rows) x 2 kv-halves (32 keys), KVBLK=64,
// QBLK=128. Grid 512 = 16 heads x 32 q-tiles; (qt=pr, 31-pr) at b, b+256.
// LDS exactly 64KB. Q pre-scaled by log2e/sqrt(HD); VT is [DM][SEQ].
// S^T = mfma(K,Q); O^T = mfma(VT,P^T); T12 cvt_pk+permlane; defer-max.
__global__ __launch_bounds__(512) void flash_attn9_kernel(
    const short* __restrict__ Q, const short* __restrict__ K,
    const short* __restrict__ VT, short* __restrict__ O) {
  __shared__ __align__(16) char LB[65536];
  const int t = threadIdx.x, lane = t & 63, w = t >> 6;   // w: 0..7
  const int hi = lane >> 5, c31 = lane & 31;
  const int s = w & 3, v = w >> 2;                // strip, kv-half
  const int id = blockIdx.x;                      // 0..511
  const int h  = (id & 7) * 2 + ((id >> 3) & 1);  // 2 heads per XCD
  const int pr = (id >> 4) & 15;                  // 0..15
  const int qt = (id < 256) ? pr : (31 - pr);     // 128-row q-tile

  auto stage = [&](int kt, int buf) {
    #pragma unroll
    for (int it = 0; it < 2; it++) {
      const int ob = it * 8192 + w * 1024;        // wave-uniform LDS byte base
      const int o  = ob + lane * 16;
      const int row = o >> 8;                     // 0..63
      const int xs = (o & 255) ^ ((row & 15) << 4);
      { const size_t src = ((size_t)(kt * 64 + row) * DM + h * HD) * 2 + xs;
        async16((const char*)K + src, LB + buf * 16384 + ob); }
      { const int d = 2 * row + (xs >> 7);
        const size_t src = ((size_t)(h * HD + d) * SEQ + (size_t)kt * 64) * 2
                         + (size_t)(xs & 127);
        async16((const char*)VT + src, LB + 32768 + buf * 16384 + ob); }
    }
  };

  const int q0 = qt * 128;
  const int nt = 2 * (qt + 1);                    // 64-key tiles
  const int qrow = q0 + s * 32 + c31;             // this lane's q-row

  stage(0, 0);

  bf16x8 qf[8];
  #pragma unroll
  for (int ss = 0; ss < 8; ss++)
    qf[ss] = *(const bf16x8*)(Q + (size_t)qrow * DM + h * HD + ss * 16 + hi * 8);

  f32x16 oacc[4] = {};
  float m = -3.0e38f, l = 0.f;

  __syncthreads();                                // stage(0) landed

  for (int kt = 0; kt < nt; kt++) {
    const int buf = kt & 1;
    if (kt + 1 < nt) stage(kt + 1, buf ^ 1);

    if (kt * 64 + v * 32 <= q0 + s * 32 + 31) {   // wave has unmasked work
      const char* KsB = LB + buf * 16384;
      const char* VsB = LB + 32768 + buf * 16384;

      f32x16 sacc = {};
      __builtin_amdgcn_s_setprio(1);
      #pragma unroll
      for (int ss = 0; ss < 8; ss++) {
        int row = v * 32 + c31;
        bf16x8 kf = *(const bf16x8*)(KsB + row * 256
                                     + ((ss * 32 + hi * 16) ^ ((row & 15) << 4)));
        sacc = __builtin_amdgcn_mfma_f32_32x32x16_bf16(kf, qf[ss], sacc, 0, 0, 0);
      }
      __builtin_amdgcn_s_setprio(0);

      float t0[8];
      #pragma unroll
      for (int r = 0; r < 8; r++) t0[r] = fmaxf(sacc[r], sacc[r + 8]);
      #pragma unroll
      for (int d = 4; d > 0; d >>= 1)
        #pragma unroll
        for (int r = 0; r < 4; r++) if (r < d) t0[r] = fmaxf(t0[r], t0[r + d]);
      float mx = t0[0];
      i32x2 mm = __builtin_amdgcn_permlane32_swap(__float_as_int(mx), __float_as_int(mx),
                                                  false, false);
      mx = fmaxf(__int_as_float(mm.x), __int_as_float(mm.y));

      if (__any(mx > m + 11.5416f)) {
        float mn = fmaxf(m, mx);
        float al = exp2r(m - mn);
        m = mn; l *= al;
        #pragma unroll
        for (int g = 0; g < 4; g++)
          #pragma unroll
          for (int r = 0; r < 16; r++) oacc[g][r] *= al;
      }

      const int rel = qrow - kt * 64 - v * 32;
      const bool maskT = (kt * 64 + v * 32 + 31) > (q0 + s * 32);
      #pragma unroll
      for (int r = 0; r < 16; r++) {
        float e = exp2r(sacc[r] - m);
        if (maskT) {
          int kl = (r & 3) + 8 * (r >> 2) + 4 * hi;
          e = (kl > rel) ? 0.f : e;
        }
        sacc[r] = e;
      }

      float s0[8];
      #pragma unroll
      for (int r = 0; r < 8; r++) s0[r] = sacc[r] + sacc[r + 8];
      #pragma unroll
      for (int d = 4; d > 0; d >>= 1)
        #pragma unroll
        for (int r = 0; r < 4; r++) if (r < d) s0[r] = s0[r] + s0[r + d];
      l += s0[0];

      bf16x8 pa[2];
      #pragma unroll
      for (int sg = 0; sg < 2; sg++) {
        int q0a = cvtpk(sacc[8 * sg + 0], sacc[8 * sg + 1]);
        int q1a = cvtpk(sacc[8 * sg + 2], sacc[8 * sg + 3]);
        int q0b = cvtpk(sacc[8 * sg + 4], sacc[8 * sg + 5]);
        int q1b = cvtpk(sacc[8 * sg + 6], sacc[8 * sg + 7]);
        i32x2 r0 = __builtin_amdgcn_permlane32_swap(q0a, q0b, false, false);
        i32x2 r1 = __builtin_amdgcn_permlane32_swap(q1a, q1b, false, false);
        union { int d[4]; bf16x8 vv; } u;
        u.d[0] = r0.x; u.d[1] = r1.x; u.d[2] = r0.y; u.d[3] = r1.y;
        pa[sg] = u.vv;
      }

      __builtin_amdgcn_s_setprio(1);
      #pragma unroll
      for (int ks = 0; ks < 2; ks++)
        #pragma unroll
        for (int g = 0; g < 4; g++) {
          int d = g * 32 + c31;
          int row = d >> 1;
          int x = (d & 1) * 128 + v * 64 + ks * 32 + hi * 16;
          bf16x8 vf = *(const bf16x8*)(VsB + row * 256 + (x ^ ((row & 15) << 4)));
          oacc[g] = __builtin_amdgcn_mfma_f32_32x32x16_bf16(vf, pa[ks], oacc[g], 0, 0, 0);
        }
      __builtin_amdgcn_s_setprio(0);
    }
    __syncthreads();
  }

  i32x2 lr = __builtin_amdgcn_permlane32_swap(__float_as_int(l), __float_as_int(l),
                                              false, false);
  l = __int_as_float(lr.x) + __int_as_float(lr.y);

  #pragma unroll
  for (int round = 0; round < 2; round++) {
    const int reg = s & 1;
    const bool active = (s >> 1) == round;
    if (active && v == 1) {
      float* Op = (float*)(LB + reg * 16384);
      #pragma unroll
      for (int g = 0; g < 4; g++)
        #pragma unroll
        for (int rr = 0; rr < 16; rr++) {
          int d = g * 32 + (rr & 3) + 8 * (rr >> 2) + 4 * hi;
          Op[d * 32 + c31] = oacc[g][rr];
        }
      if (hi == 0) {
        float* mm2 = (float*)(LB + 32768 + reg * 256) + c31 * 2;
        mm2[0] = m; mm2[1] = l;
      }
    }
    __syncthreads();
    if (active && v == 0) {
      const float* mm2 = (const float*)(LB + 32768 + reg * 256) + c31 * 2;
      float lB = mm2[1];
      float mB = (lB > 0.f) ? mm2[0] : -3.0e38f;
      float ms = fmaxf(m, mB);
      float aA = exp2r(m - ms), aB = exp2r(mB - ms);
      float linv = 1.0f / (l * aA + lB * aB);
      float sA = aA * linv, sB = aB * linv;
      const float* Op = (const float*)(LB + reg * 16384);
      #pragma unroll
      for (int g = 0; g < 4; g++)
        #pragma unroll
        for (int tt = 0; tt < 4; tt++) {
          float o[4];
          #pragma unroll
          for (int e = 0; e < 4; e++) {
            int d = g * 32 + e + 8 * tt + 4 * hi;
            o[e] = oacc[g][4 * tt + e] * sA + Op[d * 32 + c31] * sB;
          }
          u32x2 pk;
          pk.x = (unsigned)cvtpk(o[0], o[1]);
          pk.y = (unsigned)cvtpk(o[2], o[3]);
          *(u32x2*)(O + (size_t)qrow * DM + h * HD + g * 32 + tt * 8 + hi * 4) = pk;
        }
    }
    __syncthreads();
  }
}

extern "C" void kernel_launch(void* const* d_in, const int* in_sizes, int n_in,
                              void* d_out, int out_size, void* d_ws, size_t ws_size,
                              hipStream_t stream) {
  const float* x  = (const float*)d_in[0];
  const float* wq = (const float*)d_in[1];
  const float* wk = (const float*)d_in[2];
  const float* wv = (const float*)d_in[3];
  const float* wo = (const float*)d_in[4];
  float* out = (float*)d_out;

  const size_t SQDMs = (size_t)SEQ * DM;   // 8M elements
  short* Qb   = (short*)d_ws;
  short* Kb   = Qb + SQDMs;
  short* VTb  = Kb + SQDMs;
  short* Cb   = VTb + SQDMs;
  short* xbf  = Cb + SQDMs;
  short* wbuf = xbf + SQDMs;
  float2* tab = (float2*)(wbuf + (size_t)DM * DM);

  rope_tables_kernel<<<SEQ * 64 / 256, 256, 0, stream>>>(tab);
  f32_to_bf16_kernel<<<2048, 256, 0, stream>>>(x, xbf, (int)(SQDMs / 4));

  dim3 g8(SEQ / 256, DM / 128);   // 16 x 16 = 256 blocks = 1/CU
  f32_to_bf16_kernel<<<2048, 256, 0, stream>>>(wq, wbuf, DM * DM / 4);
  gemm8p_kernel<1><<<g8, 512, 0, stream>>>(xbf, wbuf, Qb, tab);
  f32_to_bf16_kernel<<<2048, 256, 0, stream>>>(wk, wbuf, DM * DM / 4);
  gemm8p_kernel<2><<<g8, 512, 0, stream>>>(xbf, wbuf, Kb, tab);
  f32_to_bf16_kernel<<<2048, 256, 0, stream>>>(wv, wbuf, DM * DM / 4);
  gemm8p_kernel<3><<<g8, 512, 0, stream>>>(xbf, wbuf, VTb, nullptr);

  flash_attn9_kernel<<<512, 512, 0, stream>>>(Qb, Kb, VTb, Cb);

  f32_to_bf16_kernel<<<2048, 256, 0, stream>>>(wo, wbuf, DM * DM / 4);
  gemm8p_kernel<0><<<g8, 512, 0, stream>>>(Cb, wbuf, out, nullptr);
}

// Round 15
// 281.142 us; speedup vs baseline: 1.1113x; 1.0083x over previous
//
#include <hip/hip_runtime.h>
#include <hip/hip_bf16.h>
#include <stdint.h>

#define SEQ 4096
#define DM 2048
#define NH 16
#define HD 128

typedef __attribute__((ext_vector_type(4)))  float f32x4;
typedef __attribute__((ext_vector_type(16))) float f32x16;
typedef __attribute__((ext_vector_type(8)))  short bf16x8;
typedef __attribute__((ext_vector_type(4)))  float float4_t;
typedef __attribute__((ext_vector_type(4)))  short s16x4;
typedef __attribute__((ext_vector_type(2)))  int   i32x2;
typedef __attribute__((ext_vector_type(2)))  unsigned u32x2;

__device__ __forceinline__ short f2bf(float f) {
  union { float f; unsigned u; } c; c.f = f;
  unsigned u = c.u;
  u += 0x7FFFu + ((u >> 16) & 1u);   // RNE
  return (short)(u >> 16);
}

__device__ __forceinline__ int cvtpk(float lo, float hi) {
  int r;
  asm("v_cvt_pk_bf16_f32 %0, %1, %2" : "=v"(r) : "v"(lo), "v"(hi));
  return r;
}

__device__ __forceinline__ float exp2r(float x) {   // raw v_exp_f32
  return __builtin_amdgcn_exp2f(x);
}

__device__ __forceinline__ void async16(const void* g, void* l) {
  __builtin_amdgcn_global_load_lds((const __attribute__((address_space(1))) void*)g,
                                   (__attribute__((address_space(3))) void*)l, 16, 0, 0);
}

__global__ __launch_bounds__(256) void rope_tables_kernel(float2* __restrict__ tab) {
  int idx = blockIdx.x * 256 + threadIdx.x;  // SEQ*64
  int s = idx >> 6, j = idx & 63;
  float invf = expf(-(float)j * (9.210340371976184f / 64.0f)); // 10000^(-j/64)
  float ang = (float)s * invf;
  tab[idx] = make_float2(cosf(ang), sinf(ang));
}

__global__ __launch_bounds__(256) void f32_to_bf16_kernel(const float* __restrict__ in,
                                                          short* __restrict__ out, int n4) {
  int stride = gridDim.x * 256;
  for (int i = blockIdx.x * 256 + threadIdx.x; i < n4; i += stride) {
    float4_t v = ((const float4_t*)in)[i];
    s16x4 r;
    #pragma unroll
    for (int u = 0; u < 4; u++) r[u] = f2bf(v[u]);
    ((s16x4*)out)[i] = r;
  }
}

// ---------------- 8-phase GEMM v2: BM=256 BN=128 BK=64, 4Mx2N waves --------
// C[M][N] = A[M][K] * B[N][K]^T, M=SEQ N=DM K=DM. Wave (wm=w>>1, wn=w&1):
// rows wm*64..+63; cols = stripes n*32+wn*16 (n=0..3) -- stripe interleave
// keeps RoPE pairs (d, d+64) in-lane (acc[m][n] ~ acc[m][n+2]).
// 2 phases/K-tile x 16 MFMA (vs r14's 4x8): half the barriers; balanced
// tiling cuts aggregate LDS reads 160->128KB/K-tile. 3-deep LDS bufs,
// vmcnt(6) once per tile (T3+T4), explicit drain on the last two tiles
// (fixes r14's latent tail race). T2 swizzle on 128B rows.
// MODE: 0 f32 C; 1 bf16+RoPE (Q, scale log2e/sqrt(HD)); 2 bf16+RoPE (K);
// 3 bf16 transposed (V^T [N][M]).
template<int MODE>
__global__ __launch_bounds__(512) void gemm8p_kernel(
    const short* __restrict__ A, const short* __restrict__ B,
    void* __restrict__ Cp, const float2* __restrict__ tab) {
  constexpr int MM = SEQ, NN = DM, K = DM;
  // As: 3 bufs x 32KB (256 rows x 128B) at 0; Bs: 3 x 16KB (128 x 128B) at 98304.
  __shared__ __align__(16) char LB[147456];
  const int t = threadIdx.x, lane = t & 63, w = t >> 6;   // w: 0..7
  const int wm = w >> 1, wn = w & 1;
  const size_t Mbase = (size_t)blockIdx.x * 256;
  const size_t Nbase = (size_t)blockIdx.y * 128;
  const int nt = K / 64;

  auto stageA = [&](int kt, int half) {   // half: rows 0-127 / 128-255
    const int buf = kt % 3, k0 = kt * 64;
    #pragma unroll
    for (int it = 0; it < 2; it++) {
      const int ob = half * 16384 + it * 8192 + w * 1024;  // wave-uniform base
      const int o = ob + lane * 16;
      const int row = o >> 7;
      const int col = (o & 127) ^ ((row & 7) << 4);
      async16((const char*)A + ((Mbase + row) * (size_t)K + k0) * 2 + col,
              LB + buf * 32768 + ob);
    }
  };
  auto stageB = [&](int kt) {
    const int buf = kt % 3, k0 = kt * 64;
    #pragma unroll
    for (int it = 0; it < 2; it++) {
      const int ob = it * 8192 + w * 1024;
      const int o = ob + lane * 16;
      const int row = o >> 7;
      const int col = (o & 127) ^ ((row & 7) << 4);
      async16((const char*)B + ((Nbase + row) * (size_t)K + k0) * 2 + col,
              LB + 98304 + buf * 16384 + ob);
    }
  };

  f32x4 acc[4][4] = {};

  stageA(0, 0); stageA(0, 1); stageB(0);
  stageA(1, 0); stageA(1, 1); stageB(1);
  asm volatile("s_waitcnt vmcnt(6)" ::: "memory");   // tile 0 landed
  __builtin_amdgcn_s_barrier();

  for (int kt = 0; kt < nt; kt++) {
    const char* AsB = LB + (kt % 3) * 32768;
    const char* BsB = LB + 98304 + (kt % 3) * 16384;
    const bool pre = (kt + 2 < nt);
    bf16x8 a[2][4], b[2][2];

    // ---- phase 0: A all m + B n01; MFMA n01 ----
    #pragma unroll
    for (int ks = 0; ks < 2; ks++)
      #pragma unroll
      for (int m = 0; m < 4; m++) {
        int row = wm * 64 + m * 16 + (lane & 15);
        a[ks][m] = *(const bf16x8*)(AsB + row * 128
                    + ((ks * 64 + (lane >> 4) * 16) ^ ((row & 7) << 4)));
      }
    #pragma unroll
    for (int ks = 0; ks < 2; ks++)
      #pragma unroll
      for (int n = 0; n < 2; n++) {
        int row = n * 32 + wn * 16 + (lane & 15);
        b[ks][n] = *(const bf16x8*)(BsB + row * 128
                    + ((ks * 64 + (lane >> 4) * 16) ^ ((row & 7) << 4)));
      }
    if (pre) { stageA(kt + 2, 0); stageA(kt + 2, 1); }
    __builtin_amdgcn_s_barrier();
    asm volatile("s_waitcnt lgkmcnt(0)" ::: "memory");
    __builtin_amdgcn_sched_barrier(0);
    __builtin_amdgcn_s_setprio(1);
    #pragma unroll
    for (int ks = 0; ks < 2; ks++)
      #pragma unroll
      for (int m = 0; m < 4; m++)
        #pragma unroll
        for (int n = 0; n < 2; n++)
          acc[m][n] = __builtin_amdgcn_mfma_f32_16x16x32_bf16(
              a[ks][m], b[ks][n], acc[m][n], 0, 0, 0);
    __builtin_amdgcn_s_setprio(0);
    __builtin_amdgcn_s_barrier();

    // ---- phase 1: B n23; MFMA n23 ----
    #pragma unroll
    for (int ks = 0; ks < 2; ks++)
      #pragma unroll
      for (int n = 0; n < 2; n++) {
        int row = (n + 2) * 32 + wn * 16 + (lane & 15);
        b[ks][n] = *(const bf16x8*)(BsB + row * 128
                    + ((ks * 64 + (lane >> 4) * 16) ^ ((row & 7) << 4)));
      }
    if (pre) stageB(kt + 2);
    if (pre) asm volatile("s_waitcnt vmcnt(6)" ::: "memory");  // kt+1 landed
    else     asm volatile("s_waitcnt vmcnt(0)" ::: "memory");  // tail drain
    __builtin_amdgcn_s_barrier();
    asm volatile("s_waitcnt lgkmcnt(0)" ::: "memory");
    __builtin_amdgcn_sched_barrier(0);
    __builtin_amdgcn_s_setprio(1);
    #pragma unroll
    for (int ks = 0; ks < 2; ks++)
      #pragma unroll
      for (int m = 0; m < 4; m++)
        #pragma unroll
        for (int n = 0; n < 2; n++)
          acc[m][n + 2] = __builtin_amdgcn_mfma_f32_16x16x32_bf16(
              a[ks][m], b[ks][n], acc[m][n + 2], 0, 0, 0);
    __builtin_amdgcn_s_setprio(0);
    __builtin_amdgcn_s_barrier();
  }

  if (MODE == 1 || MODE == 2) {
    const float SC = (MODE == 1) ? 0.12751746f : 1.0f;  // log2e/sqrt(128) | 1
    #pragma unroll
    for (int m = 0; m < 4; m++)
      #pragma unroll
      for (int n = 0; n < 2; n++)
        #pragma unroll
        for (int j = 0; j < 4; j++) {
          int row = (int)Mbase + wm * 64 + m * 16 + (lane >> 4) * 4 + j;  // seq
          int dj = n * 32 + wn * 16 + (lane & 15);                        // 0..63
          float2 cs = tab[row * 64 + dj];
          float cc = cs.x * SC, ss = cs.y * SC;
          float r1 = acc[m][n][j], r2 = acc[m][n + 2][j];
          short* C = (short*)Cp;
          C[(size_t)row * NN + Nbase + dj]      = f2bf(r1 * cc - r2 * ss);
          C[(size_t)row * NN + Nbase + dj + 64] = f2bf(r2 * cc + r1 * ss);
        }
  } else {
    #pragma unroll
    for (int m = 0; m < 4; m++)
      #pragma unroll
      for (int n = 0; n < 4; n++)
        #pragma unroll
        for (int j = 0; j < 4; j++) {
          size_t row = Mbase + wm * 64 + m * 16 + (lane >> 4) * 4 + j;
          size_t col = Nbase + n * 32 + wn * 16 + (lane & 15);
          float v = acc[m][n][j];
          if (MODE == 0) ((float*)Cp)[row * NN + col] = v;
          else           ((short*)Cp)[col * (size_t)MM + row] = f2bf(v);
        }
  }
}

// ---------------- flash attention (r10 best: 107 us, conflict-free) --------
// 512 thr, 8 waves = 4 q-strips (32 rows) x 2 kv-halves (32 keys), KVBLK=64,
// QBLK=128. Grid 512 = 16 heads x 32 q-tiles; (qt=pr, 31-pr) at b, b+256.
// LDS exactly 64KB. Q pre-scaled by log2e/sqrt(HD); VT is [DM][SEQ].
// S^T = mfma(K,Q); O^T = mfma(VT,P^T); T12 cvt_pk+permlane; defer-max.
__global__ __launch_bounds__(512) void flash_attn9_kernel(
    const short* __restrict__ Q, const short* __restrict__ K,
    const short* __restrict__ VT, short* __restrict__ O) {
  __shared__ __align__(16) char LB[65536];
  const int t = threadIdx.x, lane = t & 63, w = t >> 6;   // w: 0..7
  const int hi = lane >> 5, c31 = lane & 31;
  const int s = w & 3, v = w >> 2;                // strip, kv-half
  const int id = blockIdx.x;                      // 0..511
  const int h  = (id & 7) * 2 + ((id >> 3) & 1);  // 2 heads per XCD
  const int pr = (id >> 4) & 15;                  // 0..15
  const int qt = (id < 256) ? pr : (31 - pr);     // 128-row q-tile

  auto stage = [&](int kt, int buf) {
    #pragma unroll
    for (int it = 0; it < 2; it++) {
      const int ob = it * 8192 + w * 1024;        // wave-uniform LDS byte base
      const int o  = ob + lane * 16;
      const int row = o >> 8;                     // 0..63
      const int xs = (o & 255) ^ ((row & 15) << 4);
      { const size_t src = ((size_t)(kt * 64 + row) * DM + h * HD) * 2 + xs;
        async16((const char*)K + src, LB + buf * 16384 + ob); }
      { const int d = 2 * row + (xs >> 7);
        const size_t src = ((size_t)(h * HD + d) * SEQ + (size_t)kt * 64) * 2
                         + (size_t)(xs & 127);
        async16((const char*)VT + src, LB + 32768 + buf * 16384 + ob); }
    }
  };

  const int q0 = qt * 128;
  const int nt = 2 * (qt + 1);                    // 64-key tiles
  const int qrow = q0 + s * 32 + c31;             // this lane's q-row

  stage(0, 0);

  bf16x8 qf[8];
  #pragma unroll
  for (int ss = 0; ss < 8; ss++)
    qf[ss] = *(const bf16x8*)(Q + (size_t)qrow * DM + h * HD + ss * 16 + hi * 8);

  f32x16 oacc[4] = {};
  float m = -3.0e38f, l = 0.f;

  __syncthreads();                                // stage(0) landed

  for (int kt = 0; kt < nt; kt++) {
    const int buf = kt & 1;
    if (kt + 1 < nt) stage(kt + 1, buf ^ 1);

    if (kt * 64 + v * 32 <= q0 + s * 32 + 31) {   // wave has unmasked work
      const char* KsB = LB + buf * 16384;
      const char* VsB = LB + 32768 + buf * 16384;

      f32x16 sacc = {};
      __builtin_amdgcn_s_setprio(1);
      #pragma unroll
      for (int ss = 0; ss < 8; ss++) {
        int row = v * 32 + c31;
        bf16x8 kf = *(const bf16x8*)(KsB + row * 256
                                     + ((ss * 32 + hi * 16) ^ ((row & 15) << 4)));
        sacc = __builtin_amdgcn_mfma_f32_32x32x16_bf16(kf, qf[ss], sacc, 0, 0, 0);
      }
      __builtin_amdgcn_s_setprio(0);

      float t0[8];
      #pragma unroll
      for (int r = 0; r < 8; r++) t0[r] = fmaxf(sacc[r], sacc[r + 8]);
      #pragma unroll
      for (int d = 4; d > 0; d >>= 1)
        #pragma unroll
        for (int r = 0; r < 4; r++) if (r < d) t0[r] = fmaxf(t0[r], t0[r + d]);
      float mx = t0[0];
      i32x2 mm = __builtin_amdgcn_permlane32_swap(__float_as_int(mx), __float_as_int(mx),
                                                  false, false);
      mx = fmaxf(__int_as_float(mm.x), __int_as_float(mm.y));

      if (__any(mx > m + 11.5416f)) {
        float mn = fmaxf(m, mx);
        float al = exp2r(m - mn);
        m = mn; l *= al;
        #pragma unroll
        for (int g = 0; g < 4; g++)
          #pragma unroll
          for (int r = 0; r < 16; r++) oacc[g][r] *= al;
      }

      const int rel = qrow - kt * 64 - v * 32;
      const bool maskT = (kt * 64 + v * 32 + 31) > (q0 + s * 32);
      #pragma unroll
      for (int r = 0; r < 16; r++) {
        float e = exp2r(sacc[r] - m);
        if (maskT) {
          int kl = (r & 3) + 8 * (r >> 2) + 4 * hi;
          e = (kl > rel) ? 0.f : e;
        }
        sacc[r] = e;
      }

      float s0[8];
      #pragma unroll
      for (int r = 0; r < 8; r++) s0[r] = sacc[r] + sacc[r + 8];
      #pragma unroll
      for (int d = 4; d > 0; d >>= 1)
        #pragma unroll
        for (int r = 0; r < 4; r++) if (r < d) s0[r] = s0[r] + s0[r + d];
      l += s0[0];

      bf16x8 pa[2];
      #pragma unroll
      for (int sg = 0; sg < 2; sg++) {
        int q0a = cvtpk(sacc[8 * sg + 0], sacc[8 * sg + 1]);
        int q1a = cvtpk(sacc[8 * sg + 2], sacc[8 * sg + 3]);
        int q0b = cvtpk(sacc[8 * sg + 4], sacc[8 * sg + 5]);
        int q1b = cvtpk(sacc[8 * sg + 6], sacc[8 * sg + 7]);
        i32x2 r0 = __builtin_amdgcn_permlane32_swap(q0a, q0b, false, false);
        i32x2 r1 = __builtin_amdgcn_permlane32_swap(q1a, q1b, false, false);
        union { int d[4]; bf16x8 vv; } u;
        u.d[0] = r0.x; u.d[1] = r1.x; u.d[2] = r0.y; u.d[3] = r1.y;
        pa[sg] = u.vv;
      }

      __builtin_amdgcn_s_setprio(1);
      #pragma unroll
      for (int ks = 0; ks < 2; ks++)
        #pragma unroll
        for (int g = 0; g < 4; g++) {
          int d = g * 32 + c31;
          int row = d >> 1;
          int x = (d & 1) * 128 + v * 64 + ks * 32 + hi * 16;
          bf16x8 vf = *(const bf16x8*)(VsB + row * 256 + (x ^ ((row & 15) << 4)));
          oacc[g] = __builtin_amdgcn_mfma_f32_32x32x16_bf16(vf, pa[ks], oacc[g], 0, 0, 0);
        }
      __builtin_amdgcn_s_setprio(0);
    }
    __syncthreads();
  }

  i32x2 lr = __builtin_amdgcn_permlane32_swap(__float_as_int(l), __float_as_int(l),
                                              false, false);
  l = __int_as_float(lr.x) + __int_as_float(lr.y);

  #pragma unroll
  for (int round = 0; round < 2; round++) {
    const int reg = s & 1;
    const bool active = (s >> 1) == round;
    if (active && v == 1) {
      float* Op = (float*)(LB + reg * 16384);
      #pragma unroll
      for (int g = 0; g < 4; g++)
        #pragma unroll
        for (int rr = 0; rr < 16; rr++) {
          int d = g * 32 + (rr & 3) + 8 * (rr >> 2) + 4 * hi;
          Op[d * 32 + c31] = oacc[g][rr];
        }
      if (hi == 0) {
        float* mm2 = (float*)(LB + 32768 + reg * 256) + c31 * 2;
        mm2[0] = m; mm2[1] = l;
      }
    }
    __syncthreads();
    if (active && v == 0) {
      const float* mm2 = (const float*)(LB + 32768 + reg * 256) + c31 * 2;
      float lB = mm2[1];
      float mB = (lB > 0.f) ? mm2[0] : -3.0e38f;
      float ms = fmaxf(m, mB);
      float aA = exp2r(m - ms), aB = exp2r(mB - ms);
      float linv = 1.0f / (l * aA + lB * aB);
      float sA = aA * linv, sB = aB * linv;
      const float* Op = (const float*)(LB + reg * 16384);
      #pragma unroll
      for (int g = 0; g < 4; g++)
        #pragma unroll
        for (int tt = 0; tt < 4; tt++) {
          float o[4];
          #pragma unroll
          for (int e = 0; e < 4; e++) {
            int d = g * 32 + e + 8 * tt + 4 * hi;
            o[e] = oacc[g][4 * tt + e] * sA + Op[d * 32 + c31] * sB;
          }
          u32x2 pk;
          pk.x = (unsigned)cvtpk(o[0], o[1]);
          pk.y = (unsigned)cvtpk(o[2], o[3]);
          *(u32x2*)(O + (size_t)qrow * DM + h * HD + g * 32 + tt * 8 + hi * 4) = pk;
        }
    }
    __syncthreads();
  }
}

extern "C" void kernel_launch(void* const* d_in, const int* in_sizes, int n_in,
                              void* d_out, int out_size, void* d_ws, size_t ws_size,
                              hipStream_t stream) {
  const float* x  = (const float*)d_in[0];
  const float* wq = (const float*)d_in[1];
  const float* wk = (const float*)d_in[2];
  const float* wv = (const float*)d_in[3];
  const float* wo = (const float*)d_in[4];
  float* out = (float*)d_out;

  const size_t SQDMs = (size_t)SEQ * DM;   // 8M elements
  short* Qb   = (short*)d_ws;
  short* Kb   = Qb + SQDMs;
  short* VTb  = Kb + SQDMs;
  short* Cb   = VTb + SQDMs;
  short* xbf  = Cb + SQDMs;
  short* wbuf = xbf + SQDMs;
  float2* tab = (float2*)(wbuf + (size_t)DM * DM);

  rope_tables_kernel<<<SEQ * 64 / 256, 256, 0, stream>>>(tab);
  f32_to_bf16_kernel<<<2048, 256, 0, stream>>>(x, xbf, (int)(SQDMs / 4));

  dim3 g8(SEQ / 256, DM / 128);   // 16 x 16 = 256 blocks = 1/CU
  f32_to_bf16_kernel<<<2048, 256, 0, stream>>>(wq, wbuf, DM * DM / 4);
  gemm8p_kernel<1><<<g8, 512, 0, stream>>>(xbf, wbuf, Qb, tab);
  f32_to_bf16_kernel<<<2048, 256, 0, stream>>>(wk, wbuf, DM * DM / 4);
  gemm8p_kernel<2><<<g8, 512, 0, stream>>>(xbf, wbuf, Kb, tab);
  f32_to_bf16_kernel<<<2048, 256, 0, stream>>>(wv, wbuf, DM * DM / 4);
  gemm8p_kernel<3><<<g8, 512, 0, stream>>>(xbf, wbuf, VTb, nullptr);

  flash_attn9_kernel<<<512, 512, 0, stream>>>(Qb, Kb, VTb, Cb);

  f32_to_bf16_kernel<<<2048, 256, 0, stream>>>(wo, wbuf, DM * DM / 4);
  gemm8p_kernel<0><<<g8, 512, 0, stream>>>(Cb, wbuf, out, nullptr);
}

// Round 16
// 275.246 us; speedup vs baseline: 1.1351x; 1.0214x over previous
//
#include <hip/hip_runtime.h>
#include <hip/hip_bf16.h>
#include <stdint.h>

#define SEQ 4096
#define DM 2048
#define NH 16
#define HD 128

typedef __attribute__((ext_vector_type(4)))  float f32x4;
typedef __attribute__((ext_vector_type(16))) float f32x16;
typedef __attribute__((ext_vector_type(8)))  short bf16x8;
typedef __attribute__((ext_vector_type(4)))  float float4_t;
typedef __attribute__((ext_vector_type(4)))  short s16x4;
typedef __attribute__((ext_vector_type(2)))  int   i32x2;
typedef __attribute__((ext_vector_type(2)))  unsigned u32x2;

__device__ __forceinline__ short f2bf(float f) {
  union { float f; unsigned u; } c; c.f = f;
  unsigned u = c.u;
  u += 0x7FFFu + ((u >> 16) & 1u);   // RNE
  return (short)(u >> 16);
}

__device__ __forceinline__ int cvtpk(float lo, float hi) {
  int r;
  asm("v_cvt_pk_bf16_f32 %0, %1, %2" : "=v"(r) : "v"(lo), "v"(hi));
  return r;
}

__device__ __forceinline__ float exp2r(float x) {   // raw v_exp_f32
  return __builtin_amdgcn_exp2f(x);
}

__device__ __forceinline__ void async16(const void* g, void* l) {
  __builtin_amdgcn_global_load_lds((const __attribute__((address_space(1))) void*)g,
                                   (__attribute__((address_space(3))) void*)l, 16, 0, 0);
}

__global__ __launch_bounds__(256) void rope_tables_kernel(float2* __restrict__ tab) {
  int idx = blockIdx.x * 256 + threadIdx.x;  // SEQ*64
  int s = idx >> 6, j = idx & 63;
  float invf = expf(-(float)j * (9.210340371976184f / 64.0f)); // 10000^(-j/64)
  float ang = (float)s * invf;
  tab[idx] = make_float2(cosf(ang), sinf(ang));
}

__global__ __launch_bounds__(256) void f32_to_bf16_kernel(const float* __restrict__ in,
                                                          short* __restrict__ out, int n4) {
  int stride = gridDim.x * 256;
  for (int i = blockIdx.x * 256 + threadIdx.x; i < n4; i += stride) {
    float4_t v = ((const float4_t*)in)[i];
    s16x4 r;
    #pragma unroll
    for (int u = 0; u < 4; u++) r[u] = f2bf(v[u]);
    ((s16x4*)out)[i] = r;
  }
}

// Convert 3 weights (wq,wk,wv) into one contiguous bf16 buffer in one launch.
__global__ __launch_bounds__(256) void w3_to_bf16_kernel(
    const float* __restrict__ wq, const float* __restrict__ wk,
    const float* __restrict__ wv, short* __restrict__ out) {
  const int n4w = DM * DM / 4;              // 2^20 per weight
  int stride = gridDim.x * 256;
  for (int i = blockIdx.x * 256 + threadIdx.x; i < 3 * n4w; i += stride) {
    int j = i >> 20;                        // weight index
    int loc = i & (n4w - 1);
    const float* src = (j == 0) ? wq : (j == 1) ? wk : wv;
    float4_t v = ((const float4_t*)src)[loc];
    s16x4 r;
    #pragma unroll
    for (int u = 0; u < 4; u++) r[u] = f2bf(v[u]);
    ((s16x4*)out)[i] = r;
  }
}

// ---------------- fused QKV 8-phase GEMM: BM=256 BN=128 BK=64 --------------
// B is [6144][2048] (wq;wk;wv concat) or a single [2048][2048] weight when
// region >= 0 (fallback). Region r = y>>4 (fused) selects epilogue:
// 0 -> RoPE+scale into Qout; 1 -> RoPE into Kout; 2 -> transposed VTout.
// Wave (wm,wn) 4Mx2N, stripes keep RoPE pairs in-lane. 2 phases/K-tile,
// 3-deep LDS bufs, vmcnt(6) counted (T3+T4), tail drain. T2 swizzle.
__global__ __launch_bounds__(512) void gemm_qkv_kernel(
    const short* __restrict__ A, const short* __restrict__ B,
    short* __restrict__ Qout, short* __restrict__ Kout, short* __restrict__ VTout,
    const float2* __restrict__ tab, int region) {
  constexpr int NN = DM, K = DM, MM = SEQ;
  __shared__ __align__(16) char LB[147456];
  const int t = threadIdx.x, lane = t & 63, w = t >> 6;
  const int wm = w >> 1, wn = w & 1;
  const size_t Mbase = (size_t)blockIdx.x * 256;
  const int ry  = (region < 0) ? (blockIdx.y >> 4) : region;
  const int nyl = (region < 0) ? (blockIdx.y & 15) : blockIdx.y;
  const size_t Bbase = (size_t)blockIdx.y * 128;   // row into B buffer
  const size_t Nbase = (size_t)nyl * 128;          // col in 2048-wide output
  const int nt = K / 64;

  auto stageA = [&](int kt, int half) {
    const int buf = kt % 3, k0 = kt * 64;
    #pragma unroll
    for (int it = 0; it < 2; it++) {
      const int ob = half * 16384 + it * 8192 + w * 1024;
      const int o = ob + lane * 16;
      const int row = o >> 7;
      const int col = (o & 127) ^ ((row & 7) << 4);
      async16((const char*)A + ((Mbase + row) * (size_t)K + k0) * 2 + col,
              LB + buf * 32768 + ob);
    }
  };
  auto stageB = [&](int kt) {
    const int buf = kt % 3, k0 = kt * 64;
    #pragma unroll
    for (int it = 0; it < 2; it++) {
      const int ob = it * 8192 + w * 1024;
      const int o = ob + lane * 16;
      const int row = o >> 7;
      const int col = (o & 127) ^ ((row & 7) << 4);
      async16((const char*)B + ((Bbase + row) * (size_t)K + k0) * 2 + col,
              LB + 98304 + buf * 16384 + ob);
    }
  };

  f32x4 acc[4][4] = {};

  stageA(0, 0); stageA(0, 1); stageB(0);
  stageA(1, 0); stageA(1, 1); stageB(1);
  asm volatile("s_waitcnt vmcnt(6)" ::: "memory");
  __builtin_amdgcn_s_barrier();

  for (int kt = 0; kt < nt; kt++) {
    const char* AsB = LB + (kt % 3) * 32768;
    const char* BsB = LB + 98304 + (kt % 3) * 16384;
    const bool pre = (kt + 2 < nt);
    bf16x8 a[2][4], b[2][2];

    // ---- phase 0 ----
    #pragma unroll
    for (int ks = 0; ks < 2; ks++)
      #pragma unroll
      for (int m = 0; m < 4; m++) {
        int row = wm * 64 + m * 16 + (lane & 15);
        a[ks][m] = *(const bf16x8*)(AsB + row * 128
                    + ((ks * 64 + (lane >> 4) * 16) ^ ((row & 7) << 4)));
      }
    #pragma unroll
    for (int ks = 0; ks < 2; ks++)
      #pragma unroll
      for (int n = 0; n < 2; n++) {
        int row = n * 32 + wn * 16 + (lane & 15);
        b[ks][n] = *(const bf16x8*)(BsB + row * 128
                    + ((ks * 64 + (lane >> 4) * 16) ^ ((row & 7) << 4)));
      }
    if (pre) { stageA(kt + 2, 0); stageA(kt + 2, 1); }
    __builtin_amdgcn_s_barrier();
    asm volatile("s_waitcnt lgkmcnt(0)" ::: "memory");
    __builtin_amdgcn_sched_barrier(0);
    __builtin_amdgcn_s_setprio(1);
    #pragma unroll
    for (int ks = 0; ks < 2; ks++)
      #pragma unroll
      for (int m = 0; m < 4; m++)
        #pragma unroll
        for (int n = 0; n < 2; n++)
          acc[m][n] = __builtin_amdgcn_mfma_f32_16x16x32_bf16(
              a[ks][m], b[ks][n], acc[m][n], 0, 0, 0);
    __builtin_amdgcn_s_setprio(0);
    __builtin_amdgcn_s_barrier();

    // ---- phase 1 ----
    #pragma unroll
    for (int ks = 0; ks < 2; ks++)
      #pragma unroll
      for (int n = 0; n < 2; n++) {
        int row = (n + 2) * 32 + wn * 16 + (lane & 15);
        b[ks][n] = *(const bf16x8*)(BsB + row * 128
                    + ((ks * 64 + (lane >> 4) * 16) ^ ((row & 7) << 4)));
      }
    if (pre) stageB(kt + 2);
    if (pre) asm volatile("s_waitcnt vmcnt(6)" ::: "memory");
    else     asm volatile("s_waitcnt vmcnt(0)" ::: "memory");
    __builtin_amdgcn_s_barrier();
    asm volatile("s_waitcnt lgkmcnt(0)" ::: "memory");
    __builtin_amdgcn_sched_barrier(0);
    __builtin_amdgcn_s_setprio(1);
    #pragma unroll
    for (int ks = 0; ks < 2; ks++)
      #pragma unroll
      for (int m = 0; m < 4; m++)
        #pragma unroll
        for (int n = 0; n < 2; n++)
          acc[m][n + 2] = __builtin_amdgcn_mfma_f32_16x16x32_bf16(
              a[ks][m], b[ks][n], acc[m][n + 2], 0, 0, 0);
    __builtin_amdgcn_s_setprio(0);
    __builtin_amdgcn_s_barrier();
  }

  if (ry < 2) {
    const float SC = (ry == 0) ? 0.12751746f : 1.0f;  // log2e/sqrt(128) | 1
    short* C = (ry == 0) ? Qout : Kout;
    #pragma unroll
    for (int m = 0; m < 4; m++)
      #pragma unroll
      for (int n = 0; n < 2; n++)
        #pragma unroll
        for (int j = 0; j < 4; j++) {
          int row = (int)Mbase + wm * 64 + m * 16 + (lane >> 4) * 4 + j;  // seq
          int dj = n * 32 + wn * 16 + (lane & 15);                        // 0..63
          float2 cs = tab[row * 64 + dj];
          float cc = cs.x * SC, ss = cs.y * SC;
          float r1 = acc[m][n][j], r2 = acc[m][n + 2][j];
          C[(size_t)row * NN + Nbase + dj]      = f2bf(r1 * cc - r2 * ss);
          C[(size_t)row * NN + Nbase + dj + 64] = f2bf(r2 * cc + r1 * ss);
        }
  } else {
    #pragma unroll
    for (int m = 0; m < 4; m++)
      #pragma unroll
      for (int n = 0; n < 4; n++)
        #pragma unroll
        for (int j = 0; j < 4; j++) {
          size_t row = Mbase + wm * 64 + m * 16 + (lane >> 4) * 4 + j;
          size_t col = Nbase + n * 32 + wn * 16 + (lane & 15);
          VTout[col * (size_t)MM + row] = f2bf(acc[m][n][j]);
        }
  }
}

// ---------------- out-projection 8-phase GEMM (f32 C) ----------------------
__global__ __launch_bounds__(512) void gemm_out_kernel(
    const short* __restrict__ A, const short* __restrict__ B,
    float* __restrict__ Cp) {
  constexpr int NN = DM, K = DM;
  __shared__ __align__(16) char LB[147456];
  const int t = threadIdx.x, lane = t & 63, w = t >> 6;
  const int wm = w >> 1, wn = w & 1;
  const size_t Mbase = (size_t)blockIdx.x * 256;
  const size_t Nbase = (size_t)blockIdx.y * 128;
  const int nt = K / 64;

  auto stageA = [&](int kt, int half) {
    const int buf = kt % 3, k0 = kt * 64;
    #pragma unroll
    for (int it = 0; it < 2; it++) {
      const int ob = half * 16384 + it * 8192 + w * 1024;
      const int o = ob + lane * 16;
      const int row = o >> 7;
      const int col = (o & 127) ^ ((row & 7) << 4);
      async16((const char*)A + ((Mbase + row) * (size_t)K + k0) * 2 + col,
              LB + buf * 32768 + ob);
    }
  };
  auto stageB = [&](int kt) {
    const int buf = kt % 3, k0 = kt * 64;
    #pragma unroll
    for (int it = 0; it < 2; it++) {
      const int ob = it * 8192 + w * 1024;
      const int o = ob + lane * 16;
      const int row = o >> 7;
      const int col = (o & 127) ^ ((row & 7) << 4);
      async16((const char*)B + ((Nbase + row) * (size_t)K + k0) * 2 + col,
              LB + 98304 + buf * 16384 + ob);
    }
  };

  f32x4 acc[4][4] = {};

  stageA(0, 0); stageA(0, 1); stageB(0);
  stageA(1, 0); stageA(1, 1); stageB(1);
  asm volatile("s_waitcnt vmcnt(6)" ::: "memory");
  __builtin_amdgcn_s_barrier();

  for (int kt = 0; kt < nt; kt++) {
    const char* AsB = LB + (kt % 3) * 32768;
    const char* BsB = LB + 98304 + (kt % 3) * 16384;
    const bool pre = (kt + 2 < nt);
    bf16x8 a[2][4], b[2][2];

    #pragma unroll
    for (int ks = 0; ks < 2; ks++)
      #pragma unroll
      for (int m = 0; m < 4; m++) {
        int row = wm * 64 + m * 16 + (lane & 15);
        a[ks][m] = *(const bf16x8*)(AsB + row * 128
                    + ((ks * 64 + (lane >> 4) * 16) ^ ((row & 7) << 4)));
      }
    #pragma unroll
    for (int ks = 0; ks < 2; ks++)
      #pragma unroll
      for (int n = 0; n < 2; n++) {
        int row = n * 32 + wn * 16 + (lane & 15);
        b[ks][n] = *(const bf16x8*)(BsB + row * 128
                    + ((ks * 64 + (lane >> 4) * 16) ^ ((row & 7) << 4)));
      }
    if (pre) { stageA(kt + 2, 0); stageA(kt + 2, 1); }
    __builtin_amdgcn_s_barrier();
    asm volatile("s_waitcnt lgkmcnt(0)" ::: "memory");
    __builtin_amdgcn_sched_barrier(0);
    __builtin_amdgcn_s_setprio(1);
    #pragma unroll
    for (int ks = 0; ks < 2; ks++)
      #pragma unroll
      for (int m = 0; m < 4; m++)
        #pragma unroll
        for (int n = 0; n < 2; n++)
          acc[m][n] = __builtin_amdgcn_mfma_f32_16x16x32_bf16(
              a[ks][m], b[ks][n], acc[m][n], 0, 0, 0);
    __builtin_amdgcn_s_setprio(0);
    __builtin_amdgcn_s_barrier();

    #pragma unroll
    for (int ks = 0; ks < 2; ks++)
      #pragma unroll
      for (int n = 0; n < 2; n++) {
        int row = (n + 2) * 32 + wn * 16 + (lane & 15);
        b[ks][n] = *(const bf16x8*)(BsB + row * 128
                    + ((ks * 64 + (lane >> 4) * 16) ^ ((row & 7) << 4)));
      }
    if (pre) stageB(kt + 2);
    if (pre) asm volatile("s_waitcnt vmcnt(6)" ::: "memory");
    else     asm volatile("s_waitcnt vmcnt(0)" ::: "memory");
    __builtin_amdgcn_s_barrier();
    asm volatile("s_waitcnt lgkmcnt(0)" ::: "memory");
    __builtin_amdgcn_sched_barrier(0);
    __builtin_amdgcn_s_setprio(1);
    #pragma unroll
    for (int ks = 0; ks < 2; ks++)
      #pragma unroll
      for (int m = 0; m < 4; m++)
        #pragma unroll
        for (int n = 0; n < 2; n++)
          acc[m][n + 2] = __builtin_amdgcn_mfma_f32_16x16x32_bf16(
              a[ks][m], b[ks][n], acc[m][n + 2], 0, 0, 0);
    __builtin_amdgcn_s_setprio(0);
    __builtin_amdgcn_s_barrier();
  }

  #pragma unroll
  for (int m = 0; m < 4; m++)
    #pragma unroll
    for (int n = 0; n < 4; n++)
      #pragma unroll
      for (int j = 0; j < 4; j++) {
        size_t row = Mbase + wm * 64 + m * 16 + (lane >> 4) * 4 + j;
        size_t col = Nbase + n * 32 + wn * 16 + (lane & 15);
        Cp[row * NN + col] = acc[m][n][j];
      }
}

// ---------------- flash attention (r10 best: 107 us, conflict-free) --------
__global__ __launch_bounds__(512) void flash_attn9_kernel(
    const short* __restrict__ Q, const short* __restrict__ K,
    const short* __restrict__ VT, short* __restrict__ O) {
  __shared__ __align__(16) char LB[65536];
  const int t = threadIdx.x, lane = t & 63, w = t >> 6;   // w: 0..7
  const int hi = lane >> 5, c31 = lane & 31;
  const int s = w & 3, v = w >> 2;                // strip, kv-half
  const int id = blockIdx.x;                      // 0..511
  const int h  = (id & 7) * 2 + ((id >> 3) & 1);  // 2 heads per XCD
  const int pr = (id >> 4) & 15;                  // 0..15
  const int qt = (id < 256) ? pr : (31 - pr);     // 128-row q-tile

  auto stage = [&](int kt, int buf) {
    #pragma unroll
    for (int it = 0; it < 2; it++) {
      const int ob = it * 8192 + w * 1024;        // wave-uniform LDS byte base
      const int o  = ob + lane * 16;
      const int row = o >> 8;                     // 0..63
      const int xs = (o & 255) ^ ((row & 15) << 4);
      { const size_t src = ((size_t)(kt * 64 + row) * DM + h * HD) * 2 + xs;
        async16((const char*)K + src, LB + buf * 16384 + ob); }
      { const int d = 2 * row + (xs >> 7);
        const size_t src = ((size_t)(h * HD + d) * SEQ + (size_t)kt * 64) * 2
                         + (size_t)(xs & 127);
        async16((const char*)VT + src, LB + 32768 + buf * 16384 + ob); }
    }
  };

  const int q0 = qt * 128;
  const int nt = 2 * (qt + 1);                    // 64-key tiles
  const int qrow = q0 + s * 32 + c31;             // this lane's q-row

  stage(0, 0);

  bf16x8 qf[8];
  #pragma unroll
  for (int ss = 0; ss < 8; ss++)
    qf[ss] = *(const bf16x8*)(Q + (size_t)qrow * DM + h * HD + ss * 16 + hi * 8);

  f32x16 oacc[4] = {};
  float m = -3.0e38f, l = 0.f;

  __syncthreads();                                // stage(0) landed

  for (int kt = 0; kt < nt; kt++) {
    const int buf = kt & 1;
    if (kt + 1 < nt) stage(kt + 1, buf ^ 1);

    if (kt * 64 + v * 32 <= q0 + s * 32 + 31) {   // wave has unmasked work
      const char* KsB = LB + buf * 16384;
      const char* VsB = LB + 32768 + buf * 16384;

      f32x16 sacc = {};
      __builtin_amdgcn_s_setprio(1);
      #pragma unroll
      for (int ss = 0; ss < 8; ss++) {
        int row = v * 32 + c31;
        bf16x8 kf = *(const bf16x8*)(KsB + row * 256
                                     + ((ss * 32 + hi * 16) ^ ((row & 15) << 4)));
        sacc = __builtin_amdgcn_mfma_f32_32x32x16_bf16(kf, qf[ss], sacc, 0, 0, 0);
      }
      __builtin_amdgcn_s_setprio(0);

      float t0[8];
      #pragma unroll
      for (int r = 0; r < 8; r++) t0[r] = fmaxf(sacc[r], sacc[r + 8]);
      #pragma unroll
      for (int d = 4; d > 0; d >>= 1)
        #pragma unroll
        for (int r = 0; r < 4; r++) if (r < d) t0[r] = fmaxf(t0[r], t0[r + d]);
      float mx = t0[0];
      i32x2 mm = __builtin_amdgcn_permlane32_swap(__float_as_int(mx), __float_as_int(mx),
                                                  false, false);
      mx = fmaxf(__int_as_float(mm.x), __int_as_float(mm.y));

      if (__any(mx > m + 11.5416f)) {
        float mn = fmaxf(m, mx);
        float al = exp2r(m - mn);
        m = mn; l *= al;
        #pragma unroll
        for (int g = 0; g < 4; g++)
          #pragma unroll
          for (int r = 0; r < 16; r++) oacc[g][r] *= al;
      }

      const int rel = qrow - kt * 64 - v * 32;
      const bool maskT = (kt * 64 + v * 32 + 31) > (q0 + s * 32);
      #pragma unroll
      for (int r = 0; r < 16; r++) {
        float e = exp2r(sacc[r] - m);
        if (maskT) {
          int kl = (r & 3) + 8 * (r >> 2) + 4 * hi;
          e = (kl > rel) ? 0.f : e;
        }
        sacc[r] = e;
      }

      float s0[8];
      #pragma unroll
      for (int r = 0; r < 8; r++) s0[r] = sacc[r] + sacc[r + 8];
      #pragma unroll
      for (int d = 4; d > 0; d >>= 1)
        #pragma unroll
        for (int r = 0; r < 4; r++) if (r < d) s0[r] = s0[r] + s0[r + d];
      l += s0[0];

      bf16x8 pa[2];
      #pragma unroll
      for (int sg = 0; sg < 2; sg++) {
        int q0a = cvtpk(sacc[8 * sg + 0], sacc[8 * sg + 1]);
        int q1a = cvtpk(sacc[8 * sg + 2], sacc[8 * sg + 3]);
        int q0b = cvtpk(sacc[8 * sg + 4], sacc[8 * sg + 5]);
        int q1b = cvtpk(sacc[8 * sg + 6], sacc[8 * sg + 7]);
        i32x2 r0 = __builtin_amdgcn_permlane32_swap(q0a, q0b, false, false);
        i32x2 r1 = __builtin_amdgcn_permlane32_swap(q1a, q1b, false, false);
        union { int d[4]; bf16x8 vv; } u;
        u.d[0] = r0.x; u.d[1] = r1.x; u.d[2] = r0.y; u.d[3] = r1.y;
        pa[sg] = u.vv;
      }

      __builtin_amdgcn_s_setprio(1);
      #pragma unroll
      for (int ks = 0; ks < 2; ks++)
        #pragma unroll
        for (int g = 0; g < 4; g++) {
          int d = g * 32 + c31;
          int row = d >> 1;
          int x = (d & 1) * 128 + v * 64 + ks * 32 + hi * 16;
          bf16x8 vf = *(const bf16x8*)(VsB + row * 256 + (x ^ ((row & 15) << 4)));
          oacc[g] = __builtin_amdgcn_mfma_f32_32x32x16_bf16(vf, pa[ks], oacc[g], 0, 0, 0);
        }
      __builtin_amdgcn_s_setprio(0);
    }
    __syncthreads();
  }

  i32x2 lr = __builtin_amdgcn_permlane32_swap(__float_as_int(l), __float_as_int(l),
                                              false, false);
  l = __int_as_float(lr.x) + __int_as_float(lr.y);

  #pragma unroll
  for (int round = 0; round < 2; round++) {
    const int reg = s & 1;
    const bool active = (s >> 1) == round;
    if (active && v == 1) {
      float* Op = (float*)(LB + reg * 16384);
      #pragma unroll
      for (int g = 0; g < 4; g++)
        #pragma unroll
        for (int rr = 0; rr < 16; rr++) {
          int d = g * 32 + (rr & 3) + 8 * (rr >> 2) + 4 * hi;
          Op[d * 32 + c31] = oacc[g][rr];
        }
      if (hi == 0) {
        float* mm2 = (float*)(LB + 32768 + reg * 256) + c31 * 2;
        mm2[0] = m; mm2[1] = l;
      }
    }
    __syncthreads();
    if (active && v == 0) {
      const float* mm2 = (const float*)(LB + 32768 + reg * 256) + c31 * 2;
      float lB = mm2[1];
      float mB = (lB > 0.f) ? mm2[0] : -3.0e38f;
      float ms = fmaxf(m, mB);
      float aA = exp2r(m - ms), aB = exp2r(mB - ms);
      float linv = 1.0f / (l * aA + lB * aB);
      float sA = aA * linv, sB = aB * linv;
      const float* Op = (const float*)(LB + reg * 16384);
      #pragma unroll
      for (int g = 0; g < 4; g++)
        #pragma unroll
        for (int tt = 0; tt < 4; tt++) {
          float o[4];
          #pragma unroll
          for (int e = 0; e < 4; e++) {
            int d = g * 32 + e + 8 * tt + 4 * hi;
            o[e] = oacc[g][4 * tt + e] * sA + Op[d * 32 + c31] * sB;
          }
          u32x2 pk;
          pk.x = (unsigned)cvtpk(o[0], o[1]);
          pk.y = (unsigned)cvtpk(o[2], o[3]);
          *(u32x2*)(O + (size_t)qrow * DM + h * HD + g * 32 + tt * 8 + hi * 4) = pk;
        }
    }
    __syncthreads();
  }
}

extern "C" void kernel_launch(void* const* d_in, const int* in_sizes, int n_in,
                              void* d_out, int out_size, void* d_ws, size_t ws_size,
                              hipStream_t stream) {
  const float* x  = (const float*)d_in[0];
  const float* wq = (const float*)d_in[1];
  const float* wk = (const float*)d_in[2];
  const float* wv = (const float*)d_in[3];
  const float* wo = (const float*)d_in[4];
  float* out = (float*)d_out;

  const size_t SQDMs = (size_t)SEQ * DM;   // 8M elements
  short* Qb   = (short*)d_ws;
  short* Kb   = Qb + SQDMs;
  short* VTb  = Kb + SQDMs;
  short* Cb   = VTb + SQDMs;
  short* xbf  = Cb + SQDMs;
  short* wbuf = xbf + SQDMs;

  const bool fused = ws_size >= (size_t)107 * 1024 * 1024;
  float2* tab = (float2*)(wbuf + (fused ? (size_t)3 * DM * DM : (size_t)DM * DM));

  rope_tables_kernel<<<SEQ * 64 / 256, 256, 0, stream>>>(tab);
  f32_to_bf16_kernel<<<2048, 256, 0, stream>>>(x, xbf, (int)(SQDMs / 4));

  if (fused) {
    // one convert for wq/wk/wv, one fused QKV GEMM (768 blocks = 3/CU)
    w3_to_bf16_kernel<<<2048, 256, 0, stream>>>(wq, wk, wv, wbuf);
    gemm_qkv_kernel<<<dim3(SEQ / 256, 48), 512, 0, stream>>>(
        xbf, wbuf, Qb, Kb, VTb, tab, -1);
  } else {
    f32_to_bf16_kernel<<<2048, 256, 0, stream>>>(wq, wbuf, DM * DM / 4);
    gemm_qkv_kernel<<<dim3(SEQ / 256, 16), 512, 0, stream>>>(
        xbf, wbuf, Qb, Kb, VTb, tab, 0);
    f32_to_bf16_kernel<<<2048, 256, 0, stream>>>(wk, wbuf, DM * DM / 4);
    gemm_qkv_kernel<<<dim3(SEQ / 256, 16), 512, 0, stream>>>(
        xbf, wbuf, Qb, Kb, VTb, tab, 1);
    f32_to_bf16_kernel<<<2048, 256, 0, stream>>>(wv, wbuf, DM * DM / 4);
    gemm_qkv_kernel<<<dim3(SEQ / 256, 16), 512, 0, stream>>>(
        xbf, wbuf, Qb, Kb, VTb, tab, 2);
  }

  flash_attn9_kernel<<<512, 512, 0, stream>>>(Qb, Kb, VTb, Cb);

  f32_to_bf16_kernel<<<2048, 256, 0, stream>>>(wo, wbuf, DM * DM / 4);
  gemm_out_kernel<<<dim3(SEQ / 256, DM / 128), 512, 0, stream>>>(Cb, wbuf, out);
}

// Round 17
// 271.485 us; speedup vs baseline: 1.1509x; 1.0139x over previous
//
#include <hip/hip_runtime.h>
#include <hip/hip_bf16.h>
#include <stdint.h>

#define SEQ 4096
#define DM 2048
#define NH 16
#define HD 128

typedef __attribute__((ext_vector_type(4)))  float f32x4;
typedef __attribute__((ext_vector_type(16))) float f32x16;
typedef __attribute__((ext_vector_type(8)))  short bf16x8;
typedef __attribute__((ext_vector_type(4)))  float float4_t;
typedef __attribute__((ext_vector_type(4)))  short s16x4;
typedef __attribute__((ext_vector_type(2)))  int   i32x2;
typedef __attribute__((ext_vector_type(2)))  unsigned u32x2;

__device__ __forceinline__ short f2bf(float f) {
  union { float f; unsigned u; } c; c.f = f;
  unsigned u = c.u;
  u += 0x7FFFu + ((u >> 16) & 1u);   // RNE
  return (short)(u >> 16);
}

__device__ __forceinline__ int cvtpk(float lo, float hi) {
  int r;
  asm("v_cvt_pk_bf16_f32 %0, %1, %2" : "=v"(r) : "v"(lo), "v"(hi));
  return r;
}

__device__ __forceinline__ float exp2r(float x) {   // raw v_exp_f32
  return __builtin_amdgcn_exp2f(x);
}

__device__ __forceinline__ void async16(const void* g, void* l) {
  __builtin_amdgcn_global_load_lds((const __attribute__((address_space(1))) void*)g,
                                   (__attribute__((address_space(3))) void*)l, 16, 0, 0);
}

__global__ __launch_bounds__(256) void rope_tables_kernel(float2* __restrict__ tab) {
  int idx = blockIdx.x * 256 + threadIdx.x;  // SEQ*64
  int s = idx >> 6, j = idx & 63;
  float invf = expf(-(float)j * (9.210340371976184f / 64.0f)); // 10000^(-j/64)
  float ang = (float)s * invf;
  tab[idx] = make_float2(cosf(ang), sinf(ang));
}

__global__ __launch_bounds__(256) void f32_to_bf16_kernel(const float* __restrict__ in,
                                                          short* __restrict__ out, int n4) {
  int stride = gridDim.x * 256;
  for (int i = blockIdx.x * 256 + threadIdx.x; i < n4; i += stride) {
    float4_t v = ((const float4_t*)in)[i];
    s16x4 r;
    #pragma unroll
    for (int u = 0; u < 4; u++) r[u] = f2bf(v[u]);
    ((s16x4*)out)[i] = r;
  }
}

// Convert 3 weights (wq,wk,wv) into one contiguous bf16 buffer in one launch.
__global__ __launch_bounds__(256) void w3_to_bf16_kernel(
    const float* __restrict__ wq, const float* __restrict__ wk,
    const float* __restrict__ wv, short* __restrict__ out) {
  const int n4w = DM * DM / 4;              // 2^20 per weight
  int stride = gridDim.x * 256;
  for (int i = blockIdx.x * 256 + threadIdx.x; i < 3 * n4w; i += stride) {
    int j = i >> 20;                        // weight index
    int loc = i & (n4w - 1);
    const float* src = (j == 0) ? wq : (j == 1) ? wk : wv;
    float4_t v = ((const float4_t*)src)[loc];
    s16x4 r;
    #pragma unroll
    for (int u = 0; u < 4; u++) r[u] = f2bf(v[u]);
    ((s16x4*)out)[i] = r;
  }
}

// ---------------- fused QKV GEMM, 1-barrier pipeline: BM=256 BN=128 BK=64 --
// r16 diagnosis: 2 barriers/phase phase-lock all 8 waves -> LDS-read burst and
// MFMA burst strictly alternate (35% MfmaUtil + 21% VALU = 56% busy). Fix:
// ONE barrier per K-tile (3-deep buffers bound cross-wave skew to <1 iter);
// no internal fences -> compiler interleaves ds_read/MFMA via lgkmcnt and
// waves de-phase so one wave's MFMA overlaps another's reads.
// End-of-iter: vmcnt(6) counted (tile kt+1 landed; stage kt+2 = 6 newest in
// flight) + lgkmcnt(0) (own reads consumed -> no LDS clobber window) +
// sched_barrier(0) (MFMAs cannot sink past the raw s_barrier).
__global__ __launch_bounds__(512) void gemm_qkv_kernel(
    const short* __restrict__ A, const short* __restrict__ B,
    short* __restrict__ Qout, short* __restrict__ Kout, short* __restrict__ VTout,
    const float2* __restrict__ tab, int region) {
  constexpr int NN = DM, K = DM, MM = SEQ;
  __shared__ __align__(16) char LB[147456];
  const int t = threadIdx.x, lane = t & 63, w = t >> 6;
  const int wm = w >> 1, wn = w & 1;
  const size_t Mbase = (size_t)blockIdx.x * 256;
  const int ry  = (region < 0) ? (blockIdx.y >> 4) : region;
  const int nyl = (region < 0) ? (blockIdx.y & 15) : blockIdx.y;
  const size_t Bbase = (size_t)blockIdx.y * 128;   // row into B buffer
  const size_t Nbase = (size_t)nyl * 128;          // col in 2048-wide output
  const int nt = K / 64;

  auto stageA = [&](int kt, int half) {
    const int buf = kt % 3, k0 = kt * 64;
    #pragma unroll
    for (int it = 0; it < 2; it++) {
      const int ob = half * 16384 + it * 8192 + w * 1024;
      const int o = ob + lane * 16;
      const int row = o >> 7;
      const int col = (o & 127) ^ ((row & 7) << 4);
      async16((const char*)A + ((Mbase + row) * (size_t)K + k0) * 2 + col,
              LB + buf * 32768 + ob);
    }
  };
  auto stageB = [&](int kt) {
    const int buf = kt % 3, k0 = kt * 64;
    #pragma unroll
    for (int it = 0; it < 2; it++) {
      const int ob = it * 8192 + w * 1024;
      const int o = ob + lane * 16;
      const int row = o >> 7;
      const int col = (o & 127) ^ ((row & 7) << 4);
      async16((const char*)B + ((Bbase + row) * (size_t)K + k0) * 2 + col,
              LB + 98304 + buf * 16384 + ob);
    }
  };

  f32x4 acc[4][4] = {};

  stageA(0, 0); stageA(0, 1); stageB(0);
  stageA(1, 0); stageA(1, 1); stageB(1);
  asm volatile("s_waitcnt vmcnt(6)" ::: "memory");   // tile 0 landed
  __builtin_amdgcn_s_barrier();

  for (int kt = 0; kt < nt; kt++) {
    const char* AsB = LB + (kt % 3) * 32768;
    const char* BsB = LB + 98304 + (kt % 3) * 16384;
    const bool pre = (kt + 2 < nt);
    bf16x8 a[2][4], b[2][2], b2[2][2];

    #pragma unroll
    for (int ks = 0; ks < 2; ks++)
      #pragma unroll
      for (int m = 0; m < 4; m++) {
        int row = wm * 64 + m * 16 + (lane & 15);
        a[ks][m] = *(const bf16x8*)(AsB + row * 128
                    + ((ks * 64 + (lane >> 4) * 16) ^ ((row & 7) << 4)));
      }
    #pragma unroll
    for (int ks = 0; ks < 2; ks++)
      #pragma unroll
      for (int n = 0; n < 2; n++) {
        int row = n * 32 + wn * 16 + (lane & 15);
        b[ks][n] = *(const bf16x8*)(BsB + row * 128
                    + ((ks * 64 + (lane >> 4) * 16) ^ ((row & 7) << 4)));
      }
    if (pre) { stageA(kt + 2, 0); stageA(kt + 2, 1); stageB(kt + 2); }

    __builtin_amdgcn_s_setprio(1);
    #pragma unroll
    for (int ks = 0; ks < 2; ks++)
      #pragma unroll
      for (int m = 0; m < 4; m++)
        #pragma unroll
        for (int n = 0; n < 2; n++)
          acc[m][n] = __builtin_amdgcn_mfma_f32_16x16x32_bf16(
              a[ks][m], b[ks][n], acc[m][n], 0, 0, 0);
    __builtin_amdgcn_s_setprio(0);

    #pragma unroll
    for (int ks = 0; ks < 2; ks++)
      #pragma unroll
      for (int n = 0; n < 2; n++) {
        int row = (n + 2) * 32 + wn * 16 + (lane & 15);
        b2[ks][n] = *(const bf16x8*)(BsB + row * 128
                     + ((ks * 64 + (lane >> 4) * 16) ^ ((row & 7) << 4)));
      }
    __builtin_amdgcn_s_setprio(1);
    #pragma unroll
    for (int ks = 0; ks < 2; ks++)
      #pragma unroll
      for (int m = 0; m < 4; m++)
        #pragma unroll
        for (int n = 0; n < 2; n++)
          acc[m][n + 2] = __builtin_amdgcn_mfma_f32_16x16x32_bf16(
              a[ks][m], b2[ks][n], acc[m][n + 2], 0, 0, 0);
    __builtin_amdgcn_s_setprio(0);

    if (kt + 1 < nt) {
      if (pre) asm volatile("s_waitcnt vmcnt(6) lgkmcnt(0)" ::: "memory");
      else     asm volatile("s_waitcnt vmcnt(0) lgkmcnt(0)" ::: "memory");
      __builtin_amdgcn_sched_barrier(0);
      __builtin_amdgcn_s_barrier();
    }
  }

  if (ry < 2) {
    const float SC = (ry == 0) ? 0.12751746f : 1.0f;  // log2e/sqrt(128) | 1
    short* C = (ry == 0) ? Qout : Kout;
    #pragma unroll
    for (int m = 0; m < 4; m++)
      #pragma unroll
      for (int n = 0; n < 2; n++)
        #pragma unroll
        for (int j = 0; j < 4; j++) {
          int row = (int)Mbase + wm * 64 + m * 16 + (lane >> 4) * 4 + j;  // seq
          int dj = n * 32 + wn * 16 + (lane & 15);                        // 0..63
          float2 cs = tab[row * 64 + dj];
          float cc = cs.x * SC, ss = cs.y * SC;
          float r1 = acc[m][n][j], r2 = acc[m][n + 2][j];
          C[(size_t)row * NN + Nbase + dj]      = f2bf(r1 * cc - r2 * ss);
          C[(size_t)row * NN + Nbase + dj + 64] = f2bf(r2 * cc + r1 * ss);
        }
  } else {
    #pragma unroll
    for (int m = 0; m < 4; m++)
      #pragma unroll
      for (int n = 0; n < 4; n++)
        #pragma unroll
        for (int j = 0; j < 4; j++) {
          size_t row = Mbase + wm * 64 + m * 16 + (lane >> 4) * 4 + j;
          size_t col = Nbase + n * 32 + wn * 16 + (lane & 15);
          VTout[col * (size_t)MM + row] = f2bf(acc[m][n][j]);
        }
  }
}

// ---------------- out-projection GEMM, same 1-barrier pipeline (f32 C) -----
__global__ __launch_bounds__(512) void gemm_out_kernel(
    const short* __restrict__ A, const short* __restrict__ B,
    float* __restrict__ Cp) {
  constexpr int NN = DM, K = DM;
  __shared__ __align__(16) char LB[147456];
  const int t = threadIdx.x, lane = t & 63, w = t >> 6;
  const int wm = w >> 1, wn = w & 1;
  const size_t Mbase = (size_t)blockIdx.x * 256;
  const size_t Nbase = (size_t)blockIdx.y * 128;
  const int nt = K / 64;

  auto stageA = [&](int kt, int half) {
    const int buf = kt % 3, k0 = kt * 64;
    #pragma unroll
    for (int it = 0; it < 2; it++) {
      const int ob = half * 16384 + it * 8192 + w * 1024;
      const int o = ob + lane * 16;
      const int row = o >> 7;
      const int col = (o & 127) ^ ((row & 7) << 4);
      async16((const char*)A + ((Mbase + row) * (size_t)K + k0) * 2 + col,
              LB + buf * 32768 + ob);
    }
  };
  auto stageB = [&](int kt) {
    const int buf = kt % 3, k0 = kt * 64;
    #pragma unroll
    for (int it = 0; it < 2; it++) {
      const int ob = it * 8192 + w * 1024;
      const int o = ob + lane * 16;
      const int row = o >> 7;
      const int col = (o & 127) ^ ((row & 7) << 4);
      async16((const char*)B + ((Nbase + row) * (size_t)K + k0) * 2 + col,
              LB + 98304 + buf * 16384 + ob);
    }
  };

  f32x4 acc[4][4] = {};

  stageA(0, 0); stageA(0, 1); stageB(0);
  stageA(1, 0); stageA(1, 1); stageB(1);
  asm volatile("s_waitcnt vmcnt(6)" ::: "memory");
  __builtin_amdgcn_s_barrier();

  for (int kt = 0; kt < nt; kt++) {
    const char* AsB = LB + (kt % 3) * 32768;
    const char* BsB = LB + 98304 + (kt % 3) * 16384;
    const bool pre = (kt + 2 < nt);
    bf16x8 a[2][4], b[2][2], b2[2][2];

    #pragma unroll
    for (int ks = 0; ks < 2; ks++)
      #pragma unroll
      for (int m = 0; m < 4; m++) {
        int row = wm * 64 + m * 16 + (lane & 15);
        a[ks][m] = *(const bf16x8*)(AsB + row * 128
                    + ((ks * 64 + (lane >> 4) * 16) ^ ((row & 7) << 4)));
      }
    #pragma unroll
    for (int ks = 0; ks < 2; ks++)
      #pragma unroll
      for (int n = 0; n < 2; n++) {
        int row = n * 32 + wn * 16 + (lane & 15);
        b[ks][n] = *(const bf16x8*)(BsB + row * 128
                    + ((ks * 64 + (lane >> 4) * 16) ^ ((row & 7) << 4)));
      }
    if (pre) { stageA(kt + 2, 0); stageA(kt + 2, 1); stageB(kt + 2); }

    __builtin_amdgcn_s_setprio(1);
    #pragma unroll
    for (int ks = 0; ks < 2; ks++)
      #pragma unroll
      for (int m = 0; m < 4; m++)
        #pragma unroll
        for (int n = 0; n < 2; n++)
          acc[m][n] = __builtin_amdgcn_mfma_f32_16x16x32_bf16(
              a[ks][m], b[ks][n], acc[m][n], 0, 0, 0);
    __builtin_amdgcn_s_setprio(0);

    #pragma unroll
    for (int ks = 0; ks < 2; ks++)
      #pragma unroll
      for (int n = 0; n < 2; n++) {
        int row = (n + 2) * 32 + wn * 16 + (lane & 15);
        b2[ks][n] = *(const bf16x8*)(BsB + row * 128
                     + ((ks * 64 + (lane >> 4) * 16) ^ ((row & 7) << 4)));
      }
    __builtin_amdgcn_s_setprio(1);
    #pragma unroll
    for (int ks = 0; ks < 2; ks++)
      #pragma unroll
      for (int m = 0; m < 4; m++)
        #pragma unroll
        for (int n = 0; n < 2; n++)
          acc[m][n + 2] = __builtin_amdgcn_mfma_f32_16x16x32_bf16(
              a[ks][m], b2[ks][n], acc[m][n + 2], 0, 0, 0);
    __builtin_amdgcn_s_setprio(0);

    if (kt + 1 < nt) {
      if (pre) asm volatile("s_waitcnt vmcnt(6) lgkmcnt(0)" ::: "memory");
      else     asm volatile("s_waitcnt vmcnt(0) lgkmcnt(0)" ::: "memory");
      __builtin_amdgcn_sched_barrier(0);
      __builtin_amdgcn_s_barrier();
    }
  }

  #pragma unroll
  for (int m = 0; m < 4; m++)
    #pragma unroll
    for (int n = 0; n < 4; n++)
      #pragma unroll
      for (int j = 0; j < 4; j++) {
        size_t row = Mbase + wm * 64 + m * 16 + (lane >> 4) * 4 + j;
        size_t col = Nbase + n * 32 + wn * 16 + (lane & 15);
        Cp[row * NN + col] = acc[m][n][j];
      }
}

// ---------------- flash attention (r10 best: 107 us, conflict-free) --------
__global__ __launch_bounds__(512) void flash_attn9_kernel(
    const short* __restrict__ Q, const short* __restrict__ K,
    const short* __restrict__ VT, short* __restrict__ O) {
  __shared__ __align__(16) char LB[65536];
  const int t = threadIdx.x, lane = t & 63, w = t >> 6;   // w: 0..7
  const int hi = lane >> 5, c31 = lane & 31;
  const int s = w & 3, v = w >> 2;                // strip, kv-half
  const int id = blockIdx.x;                      // 0..511
  const int h  = (id & 7) * 2 + ((id >> 3) & 1);  // 2 heads per XCD
  const int pr = (id >> 4) & 15;                  // 0..15
  const int qt = (id < 256) ? pr : (31 - pr);     // 128-row q-tile

  auto stage = [&](int kt, int buf) {
    #pragma unroll
    for (int it = 0; it < 2; it++) {
      const int ob = it * 8192 + w * 1024;        // wave-uniform LDS byte base
      const int o  = ob + lane * 16;
      const int row = o >> 8;                     // 0..63
      const int xs = (o & 255) ^ ((row & 15) << 4);
      { const size_t src = ((size_t)(kt * 64 + row) * DM + h * HD) * 2 + xs;
        async16((const char*)K + src, LB + buf * 16384 + ob); }
      { const int d = 2 * row + (xs >> 7);
        const size_t src = ((size_t)(h * HD + d) * SEQ + (size_t)kt * 64) * 2
                         + (size_t)(xs & 127);
        async16((const char*)VT + src, LB + 32768 + buf * 16384 + ob); }
    }
  };

  const int q0 = qt * 128;
  const int nt = 2 * (qt + 1);                    // 64-key tiles
  const int qrow = q0 + s * 32 + c31;             // this lane's q-row

  stage(0, 0);

  bf16x8 qf[8];
  #pragma unroll
  for (int ss = 0; ss < 8; ss++)
    qf[ss] = *(const bf16x8*)(Q + (size_t)qrow * DM + h * HD + ss * 16 + hi * 8);

  f32x16 oacc[4] = {};
  float m = -3.0e38f, l = 0.f;

  __syncthreads();                                // stage(0) landed

  for (int kt = 0; kt < nt; kt++) {
    const int buf = kt & 1;
    if (kt + 1 < nt) stage(kt + 1, buf ^ 1);

    if (kt * 64 + v * 32 <= q0 + s * 32 + 31) {   // wave has unmasked work
      const char* KsB = LB + buf * 16384;
      const char* VsB = LB + 32768 + buf * 16384;

      f32x16 sacc = {};
      __builtin_amdgcn_s_setprio(1);
      #pragma unroll
      for (int ss = 0; ss < 8; ss++) {
        int row = v * 32 + c31;
        bf16x8 kf = *(const bf16x8*)(KsB + row * 256
                                     + ((ss * 32 + hi * 16) ^ ((row & 15) << 4)));
        sacc = __builtin_amdgcn_mfma_f32_32x32x16_bf16(kf, qf[ss], sacc, 0, 0, 0);
      }
      __builtin_amdgcn_s_setprio(0);

      float t0[8];
      #pragma unroll
      for (int r = 0; r < 8; r++) t0[r] = fmaxf(sacc[r], sacc[r + 8]);
      #pragma unroll
      for (int d = 4; d > 0; d >>= 1)
        #pragma unroll
        for (int r = 0; r < 4; r++) if (r < d) t0[r] = fmaxf(t0[r], t0[r + d]);
      float mx = t0[0];
      i32x2 mm = __builtin_amdgcn_permlane32_swap(__float_as_int(mx), __float_as_int(mx),
                                                  false, false);
      mx = fmaxf(__int_as_float(mm.x), __int_as_float(mm.y));

      if (__any(mx > m + 11.5416f)) {
        float mn = fmaxf(m, mx);
        float al = exp2r(m - mn);
        m = mn; l *= al;
        #pragma unroll
        for (int g = 0; g < 4; g++)
          #pragma unroll
          for (int r = 0; r < 16; r++) oacc[g][r] *= al;
      }

      const int rel = qrow - kt * 64 - v * 32;
      const bool maskT = (kt * 64 + v * 32 + 31) > (q0 + s * 32);
      #pragma unroll
      for (int r = 0; r < 16; r++) {
        float e = exp2r(sacc[r] - m);
        if (maskT) {
          int kl = (r & 3) + 8 * (r >> 2) + 4 * hi;
          e = (kl > rel) ? 0.f : e;
        }
        sacc[r] = e;
      }

      float s0[8];
      #pragma unroll
      for (int r = 0; r < 8; r++) s0[r] = sacc[r] + sacc[r + 8];
      #pragma unroll
      for (int d = 4; d > 0; d >>= 1)
        #pragma unroll
        for (int r = 0; r < 4; r++) if (r < d) s0[r] = s0[r] + s0[r + d];
      l += s0[0];

      bf16x8 pa[2];
      #pragma unroll
      for (int sg = 0; sg < 2; sg++) {
        int q0a = cvtpk(sacc[8 * sg + 0], sacc[8 * sg + 1]);
        int q1a = cvtpk(sacc[8 * sg + 2], sacc[8 * sg + 3]);
        int q0b = cvtpk(sacc[8 * sg + 4], sacc[8 * sg + 5]);
        int q1b = cvtpk(sacc[8 * sg + 6], sacc[8 * sg + 7]);
        i32x2 r0 = __builtin_amdgcn_permlane32_swap(q0a, q0b, false, false);
        i32x2 r1 = __builtin_amdgcn_permlane32_swap(q1a, q1b, false, false);
        union { int d[4]; bf16x8 vv; } u;
        u.d[0] = r0.x; u.d[1] = r1.x; u.d[2] = r0.y; u.d[3] = r1.y;
        pa[sg] = u.vv;
      }

      __builtin_amdgcn_s_setprio(1);
      #pragma unroll
      for (int ks = 0; ks < 2; ks++)
        #pragma unroll
        for (int g = 0; g < 4; g++) {
          int d = g * 32 + c31;
          int row = d >> 1;
          int x = (d & 1) * 128 + v * 64 + ks * 32 + hi * 16;
          bf16x8 vf = *(const bf16x8*)(VsB + row * 256 + (x ^ ((row & 15) << 4)));
          oacc[g] = __builtin_amdgcn_mfma_f32_32x32x16_bf16(vf, pa[ks], oacc[g], 0, 0, 0);
        }
      __builtin_amdgcn_s_setprio(0);
    }
    __syncthreads();
  }

  i32x2 lr = __builtin_amdgcn_permlane32_swap(__float_as_int(l), __float_as_int(l),
                                              false, false);
  l = __int_as_float(lr.x) + __int_as_float(lr.y);

  #pragma unroll
  for (int round = 0; round < 2; round++) {
    const int reg = s & 1;
    const bool active = (s >> 1) == round;
    if (active && v == 1) {
      float* Op = (float*)(LB + reg * 16384);
      #pragma unroll
      for (int g = 0; g < 4; g++)
        #pragma unroll
        for (int rr = 0; rr < 16; rr++) {
          int d = g * 32 + (rr & 3) + 8 * (rr >> 2) + 4 * hi;
          Op[d * 32 + c31] = oacc[g][rr];
        }
      if (hi == 0) {
        float* mm2 = (float*)(LB + 32768 + reg * 256) + c31 * 2;
        mm2[0] = m; mm2[1] = l;
      }
    }
    __syncthreads();
    if (active && v == 0) {
      const float* mm2 = (const float*)(LB + 32768 + reg * 256) + c31 * 2;
      float lB = mm2[1];
      float mB = (lB > 0.f) ? mm2[0] : -3.0e38f;
      float ms = fmaxf(m, mB);
      float aA = exp2r(m - ms), aB = exp2r(mB - ms);
      float linv = 1.0f / (l * aA + lB * aB);
      float sA = aA * linv, sB = aB * linv;
      const float* Op = (const float*)(LB + reg * 16384);
      #pragma unroll
      for (int g = 0; g < 4; g++)
        #pragma unroll
        for (int tt = 0; tt < 4; tt++) {
          float o[4];
          #pragma unroll
          for (int e = 0; e < 4; e++) {
            int d = g * 32 + e + 8 * tt + 4 * hi;
            o[e] = oacc[g][4 * tt + e] * sA + Op[d * 32 + c31] * sB;
          }
          u32x2 pk;
          pk.x = (unsigned)cvtpk(o[0], o[1]);
          pk.y = (unsigned)cvtpk(o[2], o[3]);
          *(u32x2*)(O + (size_t)qrow * DM + h * HD + g * 32 + tt * 8 + hi * 4) = pk;
        }
    }
    __syncthreads();
  }
}

extern "C" void kernel_launch(void* const* d_in, const int* in_sizes, int n_in,
                              void* d_out, int out_size, void* d_ws, size_t ws_size,
                              hipStream_t stream) {
  const float* x  = (const float*)d_in[0];
  const float* wq = (const float*)d_in[1];
  const float* wk = (const float*)d_in[2];
  const float* wv = (const float*)d_in[3];
  const float* wo = (const float*)d_in[4];
  float* out = (float*)d_out;

  const size_t SQDMs = (size_t)SEQ * DM;   // 8M elements
  short* Qb   = (short*)d_ws;
  short* Kb   = Qb + SQDMs;
  short* VTb  = Kb + SQDMs;
  short* Cb   = VTb + SQDMs;
  short* xbf  = Cb + SQDMs;
  short* wbuf = xbf + SQDMs;

  const bool fused = ws_size >= (size_t)107 * 1024 * 1024;
  float2* tab = (float2*)(wbuf + (fused ? (size_t)3 * DM * DM : (size_t)DM * DM));

  rope_tables_kernel<<<SEQ * 64 / 256, 256, 0, stream>>>(tab);
  f32_to_bf16_kernel<<<2048, 256, 0, stream>>>(x, xbf, (int)(SQDMs / 4));

  if (fused) {
    w3_to_bf16_kernel<<<2048, 256, 0, stream>>>(wq, wk, wv, wbuf);
    gemm_qkv_kernel<<<dim3(SEQ / 256, 48), 512, 0, stream>>>(
        xbf, wbuf, Qb, Kb, VTb, tab, -1);
  } else {
    f32_to_bf16_kernel<<<2048, 256, 0, stream>>>(wq, wbuf, DM * DM / 4);
    gemm_qkv_kernel<<<dim3(SEQ / 256, 16), 512, 0, stream>>>(
        xbf, wbuf, Qb, Kb, VTb, tab, 0);
    f32_to_bf16_kernel<<<2048, 256, 0, stream>>>(wk, wbuf, DM * DM / 4);
    gemm_qkv_kernel<<<dim3(SEQ / 256, 16), 512, 0, stream>>>(
        xbf, wbuf, Qb, Kb, VTb, tab, 1);
    f32_to_bf16_kernel<<<2048, 256, 0, stream>>>(wv, wbuf, DM * DM / 4);
    gemm_qkv_kernel<<<dim3(SEQ / 256, 16), 512, 0, stream>>>(
        xbf, wbuf, Qb, Kb, VTb, tab, 2);
  }

  flash_attn9_kernel<<<512, 512, 0, stream>>>(Qb, Kb, VTb, Cb);

  f32_to_bf16_kernel<<<2048, 256, 0, stream>>>(wo, wbuf, DM * DM / 4);
  gemm_out_kernel<<<dim3(SEQ / 256, DM / 128), 512, 0, stream>>>(Cb, wbuf, out);
}